// Round 8
// baseline (386.035 us; speedup 1.0000x reference)
//
#include <hip/hip_runtime.h>
#include <hip/hip_bf16.h>
#include <float.h>

// Performer FastAttention (FAVOR+), MFMA bf16-split v4.1.
// Round 8: round-7 structure + amdgpu_waves_per_eu(4,4) pin to kill the
// register-spill scratch traffic (WRITE_SIZE 377MB -> ~110MB expected).

typedef __attribute__((ext_vector_type(8))) short short8v;
typedef __attribute__((ext_vector_type(4))) short short4v;
typedef __attribute__((ext_vector_type(4))) float f32x4;

#define MFMA16(a, b, c) __builtin_amdgcn_mfma_f32_16x16x32_bf16(a, b, c, 0, 0, 0)

namespace {
constexpr int Nn = 4096, Dd = 64, BHn = 96;
constexpr float kNorm = 0.35355339059327379f;  // 64^-0.25
constexpr float kDiagCoef = 0.0625f;           // 0.5 * 64^-0.5
constexpr float kEps = 1e-4f;

constexpr size_t oStab  = 0;                                   // 96 u32
constexpr size_t oEsum  = 512;                                 // 96*256 f32
constexpr size_t oVsum  = oEsum + (size_t)BHn * 256 * 4;       // 96*64 f32
constexpr size_t oKshat = oVsum + (size_t)BHn * 64 * 4;        // 96*256 f32
constexpr size_t oCtxE  = oKshat + (size_t)BHn * 256 * 4;      // 96*256*64 f32
constexpr size_t oCtH   = oCtxE + (size_t)BHn * 256 * 64 * 4;  // 96*64*256 bf16
constexpr size_t oCtL   = oCtH + (size_t)BHn * 64 * 256 * 2;
constexpr size_t oPh    = oCtL + (size_t)BHn * 64 * 256 * 2;   // 256*64 bf16
constexpr size_t oPl    = oPh + (size_t)256 * 64 * 2;
constexpr size_t kZeroBytes = oCtH;  // zero stab..ctxE accumulators
}

static __device__ __forceinline__ unsigned floatKey(float f) {
  unsigned b = __float_as_uint(f);
  return (b & 0x80000000u) ? ~b : (b | 0x80000000u);
}
static __device__ __forceinline__ float keyToFloat(unsigned k) {
  unsigned b = (k & 0x80000000u) ? (k & 0x7fffffffu) : ~k;
  return __uint_as_float(b);
}
static __device__ __forceinline__ short f2bf(float x) {
  union { __hip_bfloat16 h; short s; } u;
  u.h = __float2bfloat16(x);
  return u.s;
}
static __device__ __forceinline__ float bf2f(short s) {
  return __uint_as_float(((unsigned)(unsigned short)s) << 16);
}
static __device__ __forceinline__ void splitbf(float x, short& h, short& l) {
  h = f2bf(x);
  l = f2bf(x - bf2f(h));
}
static __device__ __forceinline__ int sw8(int row, int col)  { return col ^ ((row & 7) << 3); }
static __device__ __forceinline__ int sw16(int row, int col) { return col ^ ((row & 15) << 3); }

// ---------------------------------------------------------------------------
// prep: split proj into bf16 hi/lo, linear [m][d] layout in ws.
// ---------------------------------------------------------------------------
__global__ void perf_prep(const float* __restrict__ proj, short* __restrict__ Ph,
                          short* __restrict__ Pl) {
  const int i = (blockIdx.x * 256 + threadIdx.x) * 4;  // 16384 elems
  float4 v = *(const float4*)(proj + i);
  float xs[4] = {v.x, v.y, v.z, v.w};
  short4v h, l;
#pragma unroll
  for (int j = 0; j < 4; ++j) {
    short hh, ll;
    splitbf(xs[j], hh, ll);
    h[j] = hh;
    l[j] = ll;
  }
  *(short4v*)(Ph + i) = h;
  *(short4v*)(Pl + i) = l;
}

// ---------------------------------------------------------------------------
// kside: grid (96, 16), block 512 (8 waves). 256 k-rows/block, 4 subs of 64.
// Wave w owns m-strip w*32..+32. proj frags in regs; dd -> E -> ctx all
// wave-local via private scratch (swizzled). 2 barriers per sub.
// waves_per_eu pinned to 4 (128 regs/wave, 2 blocks/CU, no spill).
// ---------------------------------------------------------------------------
__global__ __launch_bounds__(512)
__attribute__((amdgpu_waves_per_eu(4, 4))) void perf_kside(
    const float* __restrict__ K, const float* __restrict__ V,
    const short* __restrict__ PhG, const short* __restrict__ PlG,
    unsigned* __restrict__ stabKey, float* __restrict__ EsumG,
    float* __restrict__ VsumG, float* __restrict__ ctxEG) {
  const int t = threadIdx.x, bh = blockIdx.x, chunk = blockIdx.y;
  const int w = t >> 6, l = t & 63;
  const int lhi = l >> 4, llo = l & 15;
  const int koff = lhi * 8;

  __shared__ short Kh[64][64], Kl[64][64];
  __shared__ short Vh[64][64], Vl[64][64];      // V^T: [e][n]
  __shared__ short EsH[8][16][64], EsL[8][16][64];  // wave-private E^T scratch
  __shared__ float diag[64];
  __shared__ float rpartV[8][64];
  __shared__ float wpmax[8];

  // proj fragments in registers (wave's 32-m strip, both kb slices, hi+lo)
  short8v prh[2][2], prl[2][2];
#pragma unroll
  for (int mt = 0; mt < 2; ++mt)
#pragma unroll
    for (int kb = 0; kb < 2; ++kb) {
      const int m = w * 32 + mt * 16 + llo;
      prh[mt][kb] = *(const short8v*)(PhG + m * 64 + kb * 32 + koff);
      prl[mt][kb] = *(const short8v*)(PlG + m * 64 + kb * 32 + koff);
    }

  float mx = -FLT_MAX, vsum_r = 0.f;
  f32x4 cacc[2][4];
  float es[2] = {0.f, 0.f};
#pragma unroll
  for (int a = 0; a < 2; ++a)
#pragma unroll
    for (int b = 0; b < 4; ++b) cacc[a][b] = f32x4{0.f, 0.f, 0.f, 0.f};

  char* esh = (char*)&EsH[w][0][0] + llo * 128;
  char* esl = (char*)&EsL[w][0][0] + llo * 128;
  const int swz = (llo & 7) << 4;

  const size_t base = ((size_t)bh * Nn + chunk * 256) * Dd;

  for (int sub = 0; sub < 4; ++sub) {
    __syncthreads();  // prev sub's consumers done with Kh/Vh
    {  // stage K rows (split + diag partial), coalesced
      const int n = t >> 3, d0 = (t & 7) * 8;
      const float* ks = K + base + (size_t)(sub * 64 + n) * 64 + d0;
      const float4 a = *(const float4*)ks;
      const float4 b = *(const float4*)(ks + 4);
      float xs[8] = {a.x, a.y, a.z, a.w, b.x, b.y, b.z, b.w};
      float s = 0.f;
#pragma unroll
      for (int i = 0; i < 8; ++i) s = fmaf(xs[i], xs[i], s);
      s += __shfl_xor(s, 1); s += __shfl_xor(s, 2); s += __shfl_xor(s, 4);
      if ((t & 7) == 0) diag[n] = s * kDiagCoef;
      short8v h8, l8;
#pragma unroll
      for (int i = 0; i < 8; ++i) {
        short hh, ll;
        splitbf(kNorm * xs[i], hh, ll);
        h8[i] = hh; l8[i] = ll;
      }
      const int c = sw8(n, d0);
      *(short8v*)&Kh[n][c] = h8;
      *(short8v*)&Kl[n][c] = l8;
    }
    {  // stage V^T by transposed-coalesced global reads (+vsum)
      const int e = l, n0 = w * 8;
      const float* vs = V + base + (size_t)(sub * 64 + n0) * 64 + e;
      short8v h8, l8;
#pragma unroll
      for (int i = 0; i < 8; ++i) {
        float xv = vs[i * 64];
        vsum_r += xv;
        short hh, ll;
        splitbf(xv, hh, ll);
        h8[i] = hh; l8[i] = ll;
      }
      const int c = sw8(e, n0);
      *(short8v*)&Vh[e][c] = h8;
      *(short8v*)&Vl[e][c] = l8;
    }
    __syncthreads();  // tiles ready

#pragma unroll
    for (int mt = 0; mt < 2; ++mt) {
      float esa = 0.f;
#pragma unroll
      for (int b = 0; b < 4; ++b) {
        const int arow = b * 16 + llo;
        f32x4 acc = f32x4{0.f, 0.f, 0.f, 0.f};
#pragma unroll
        for (int kb = 0; kb < 2; ++kb) {
          const int c = sw8(arow, kb * 32 + koff);
          short8v ah = *(const short8v*)&Kh[arow][c];
          short8v al = *(const short8v*)&Kl[arow][c];
          acc = MFMA16(ah, prh[mt][kb], acc);
          acc = MFMA16(ah, prl[mt][kb], acc);
          acc = MFMA16(al, prh[mt][kb], acc);
        }
        // lane holds dd[n = b*16 + lhi*4 + jj][m = w*32 + mt*16 + llo]
        unsigned wH[2], wL[2];
#pragma unroll
        for (int q = 0; q < 2; ++q) {
          short h0, l0, h1, l1;
          float dd0 = acc[2 * q + 0];
          float dd1 = acc[2 * q + 1];
          mx = fmaxf(mx, fmaxf(dd0, dd1));
          float E0 = __expf(dd0 - diag[b * 16 + lhi * 4 + 2 * q + 0]);
          float E1 = __expf(dd1 - diag[b * 16 + lhi * 4 + 2 * q + 1]);
          esa += E0 + E1;
          splitbf(E0, h0, l0);
          splitbf(E1, h1, l1);
          wH[q] = (unsigned)(unsigned short)h0 | ((unsigned)(unsigned short)h1 << 16);
          wL[q] = (unsigned)(unsigned short)l0 | ((unsigned)(unsigned short)l1 << 16);
        }
        const int off = (b * 32 + lhi * 8) ^ swz;
        uint2 uh; uh.x = wH[0]; uh.y = wH[1];
        uint2 ul; ul.x = wL[0]; ul.y = wL[1];
        *(uint2*)(esh + off) = uh;
        *(uint2*)(esl + off) = ul;
      }
      es[mt] += esa;
      // ctx GEMM: A = E^T from private scratch, B = V^T from LDS
#pragma unroll
      for (int s = 0; s < 2; ++s) {
        const int roff = (s * 64 + lhi * 16) ^ swz;
        short8v ah8 = *(const short8v*)(esh + roff);
        short8v al8 = *(const short8v*)(esl + roff);
#pragma unroll
        for (int et = 0; et < 4; ++et) {
          const int ecol = et * 16 + llo;
          const int c = sw8(ecol, s * 32 + koff);
          short8v vh8 = *(const short8v*)&Vh[ecol][c];
          short8v vl8 = *(const short8v*)&Vl[ecol][c];
          f32x4 a2 = cacc[mt][et];
          a2 = MFMA16(ah8, vh8, a2);
          a2 = MFMA16(ah8, vl8, a2);
          a2 = MFMA16(al8, vh8, a2);
          cacc[mt][et] = a2;
        }
      }
    }
  }

  // reductions
#pragma unroll
  for (int off = 32; off; off >>= 1) mx = fmaxf(mx, __shfl_xor(mx, off));
  if (l == 0) wpmax[w] = mx;
#pragma unroll
  for (int mt = 0; mt < 2; ++mt) {
    float v2 = es[mt];
    v2 += __shfl_xor(v2, 16);
    v2 += __shfl_xor(v2, 32);
    if (l < 16) atomicAdd(&EsumG[bh * 256 + w * 32 + mt * 16 + l], v2);
  }
  rpartV[w][l] = vsum_r;
  __syncthreads();
  if (t < 64) {
    float s2 = 0.f;
#pragma unroll
    for (int w2 = 0; w2 < 8; ++w2) s2 += rpartV[w2][t];
    atomicAdd(&VsumG[bh * 64 + t], s2);
  }
  if (t == 0) {
    float b = wpmax[0];
#pragma unroll
    for (int w2 = 1; w2 < 8; ++w2) b = fmaxf(b, wpmax[w2]);
    atomicMax(stabKey + bh, floatKey(b));
  }
#pragma unroll
  for (int mt = 0; mt < 2; ++mt)
#pragma unroll
    for (int et = 0; et < 4; ++et)
#pragma unroll
      for (int jj = 0; jj < 4; ++jj) {
        const int m2 = w * 32 + mt * 16 + lhi * 4 + jj;
        const int e2 = et * 16 + llo;
        atomicAdd(&ctxEG[((size_t)bh * 256 + m2) * 64 + e2], cacc[mt][et][jj]);
      }
}

// ---------------------------------------------------------------------------
// combine: kshat[m] = e^{-stab}*Esum + eps*N; ctxhat -> transposed bf16 pair.
// ---------------------------------------------------------------------------
__global__ __launch_bounds__(256) void perf_combine(
    const unsigned* __restrict__ stabKey, const float* __restrict__ EsumG,
    const float* __restrict__ VsumG, const float* __restrict__ ctxEG,
    float* __restrict__ kshatG, short* __restrict__ ctHG, short* __restrict__ ctLG) {
  const int bh = blockIdx.x, t = threadIdx.x;
  const float esc = __expf(-keyToFloat(stabKey[bh]));
  kshatG[bh * 256 + t] = esc * EsumG[bh * 256 + t] + kEps * 4096.0f;
  for (int e = 0; e < 64; ++e) {
    const float v2 = esc * ctxEG[((size_t)bh * 256 + t) * 64 + e] + kEps * VsumG[bh * 64 + e];
    short hh, ll;
    splitbf(v2, hh, ll);
    ctHG[((size_t)bh * 64 + e) * 256 + t] = hh;
    ctLG[((size_t)bh * 64 + e) * 256 + t] = ll;
  }
}

// ---------------------------------------------------------------------------
// qside: grid (96, 64), block 512. 64 q-rows/block. LDS 65.5K -> 2 blocks/CU.
// proj staged per-128-half (32K, reused as ctT); dd 2 phases; q' hi-only with
// den from same rounded weights; out GEMM 2-term. waves_per_eu pinned to 4.
// ---------------------------------------------------------------------------
__global__ __launch_bounds__(512)
__attribute__((amdgpu_waves_per_eu(4, 4))) void perf_qside(
    const float* __restrict__ Q, const short* __restrict__ PhG,
    const short* __restrict__ PlG, const float* __restrict__ kshatG,
    const short* __restrict__ ctHG, const short* __restrict__ ctLG,
    float* __restrict__ out) {
  const int t = threadIdx.x, bh = blockIdx.x, rb = blockIdx.y;
  const int w = t >> 6, l = t & 63;
  const int rt = w & 3, ms = w >> 2;
  const int lhi = l >> 4, llo = l & 15;
  const int koff = lhi * 8;

  __shared__ short Ph[128][64], Pl[128][64];  // per-phase proj; reused as ctT[64][128]
  __shared__ short qph[64][256];              // q' bf16 (hi only)
  __shared__ float kshatL[256];
  __shared__ unsigned rmaxKey[64];
  __shared__ float denL[64];

  if (t < 64) { rmaxKey[t] = 0u; denL[t] = 0.f; }
  if (t < 256) kshatL[t] = kshatG[bh * 256 + t];

  const int r = rt * 16 + llo;  // this lane's q-row

  // Q fragments + diag (global direct; folded norm)
  short8v qh[2], ql[2];
  float dgq;
  {
    const float* qs = Q + ((size_t)bh * Nn + rb * 64 + r) * 64 + koff;
    float4 a0 = *(const float4*)qs;
    float4 a1 = *(const float4*)(qs + 4);
    float4 b0 = *(const float4*)(qs + 32);
    float4 b1 = *(const float4*)(qs + 36);
    float xs[16] = {a0.x, a0.y, a0.z, a0.w, a1.x, a1.y, a1.z, a1.w,
                    b0.x, b0.y, b0.z, b0.w, b1.x, b1.y, b1.z, b1.w};
    float s = 0.f;
#pragma unroll
    for (int i = 0; i < 16; ++i) s = fmaf(xs[i], xs[i], s);
    s += __shfl_xor(s, 16);
    s += __shfl_xor(s, 32);
    dgq = s * kDiagCoef;
#pragma unroll
    for (int kb = 0; kb < 2; ++kb) {
      short8v h8, l8;
#pragma unroll
      for (int i = 0; i < 8; ++i) {
        short hh, ll;
        splitbf(kNorm * xs[kb * 8 + i], hh, ll);
        h8[i] = hh; l8[i] = ll;
      }
      qh[kb] = h8; ql[kb] = l8;
    }
  }

  // dd GEMM in 2 phases of 128 m (proj half staged per phase)
  f32x4 dacc[8];
#pragma unroll
  for (int ph = 0; ph < 2; ++ph) {
    __syncthreads();  // init / prev-phase dd reads done
    {  // stage proj half ph
      const int i = t >> 2, d0 = (t & 3) * 16;
      const short* gh = PhG + (ph * 128 + i) * 64 + d0;
      const short* gl = PlG + (ph * 128 + i) * 64 + d0;
      const int c0 = sw8(i, d0), c1 = sw8(i, d0 + 8);
      *(short8v*)&Ph[i][c0] = *(const short8v*)gh;
      *(short8v*)&Ph[i][c1] = *(const short8v*)(gh + 8);
      *(short8v*)&Pl[i][c0] = *(const short8v*)gl;
      *(short8v*)&Pl[i][c1] = *(const short8v*)(gl + 8);
    }
    __syncthreads();
#pragma unroll
    for (int mt = 0; mt < 4; ++mt) {
      const int mrow = ms * 64 + mt * 16 + llo;
      f32x4 acc = f32x4{0.f, 0.f, 0.f, 0.f};
#pragma unroll
      for (int kb = 0; kb < 2; ++kb) {
        const int c = sw8(mrow, kb * 32 + koff);
        short8v pbh = *(const short8v*)&Ph[mrow][c];
        short8v pbl = *(const short8v*)&Pl[mrow][c];
        acc = MFMA16(pbh, qh[kb], acc);
        acc = MFMA16(pbh, ql[kb], acc);
        acc = MFMA16(pbl, qh[kb], acc);
      }
      dacc[ph * 4 + mt] = acc;  // dd[m = ph*128+ms*64+mt*16+lhi*4+jj][r]
    }
  }

  // rowmax over this wave's 128 m's, merged across ms pair via LDS
  {
    float mx = dacc[0][0];
#pragma unroll
    for (int i = 0; i < 8; ++i)
#pragma unroll
      for (int jj = 0; jj < 4; ++jj) mx = fmaxf(mx, dacc[i][jj]);
    mx = fmaxf(mx, __shfl_xor(mx, 16));
    mx = fmaxf(mx, __shfl_xor(mx, 32));
    if (l < 16) atomicMax(&rmaxKey[rt * 16 + l], floatKey(mx));
  }
  __syncthreads();

  // exp -> q' (bf16 hi), den from the SAME rounded weights
  {
    const float shift = dgq + keyToFloat(rmaxKey[r]);
    float den = 0.f;
#pragma unroll
    for (int i = 0; i < 8; ++i) {
      const int m0 = (i >> 2) * 128 + ms * 64 + (i & 3) * 16 + lhi * 4;
      const f32x4 ksv = *(const f32x4*)&kshatL[m0];
      short4v h4;
#pragma unroll
      for (int jj = 0; jj < 4; ++jj) {
        float qv = __expf(dacc[i][jj] - shift) + kEps;
        short hh = f2bf(qv);
        h4[jj] = hh;
        den = fmaf(bf2f(hh), ksv[jj], den);  // consistent with numerator
      }
      const int c = m0 ^ ((r & 31) << 3);
      *(short4v*)&qph[r][c] = h4;
    }
    den += __shfl_xor(den, 16);
    den += __shfl_xor(den, 32);
    if (l < 16) atomicAdd(&denL[rt * 16 + l], den);
  }

  // output GEMM: ctT staged per m-half into reused Ph/Pl space; 2-term
  short(*ctTh)[128] = (short(*)[128])Ph;
  short(*ctTl)[128] = (short(*)[128])Pl;
  f32x4 oacc[2] = {f32x4{0.f, 0.f, 0.f, 0.f}, f32x4{0.f, 0.f, 0.f, 0.f}};
#pragma unroll
  for (int mh2 = 0; mh2 < 2; ++mh2) {
    __syncthreads();  // qp/den writes done (mh2=0) / prev MFMAs done (mh2=1)
    {  // stage ctxhatT half
      const int e = t >> 3, mg = t & 7;
      const short* gh = ctHG + ((size_t)bh * 64 + e) * 256 + mh2 * 128 + mg * 16;
      const short* gl = ctLG + ((size_t)bh * 64 + e) * 256 + mh2 * 128 + mg * 16;
      short8v a0 = *(const short8v*)gh;
      short8v a1 = *(const short8v*)(gh + 8);
      short8v b0 = *(const short8v*)gl;
      short8v b1 = *(const short8v*)(gl + 8);
      *(short8v*)&ctTh[e][sw16(e, mg * 16)] = a0;
      *(short8v*)&ctTh[e][sw16(e, mg * 16 + 8)] = a1;
      *(short8v*)&ctTl[e][sw16(e, mg * 16)] = b0;
      *(short8v*)&ctTl[e][sw16(e, mg * 16 + 8)] = b1;
    }
    __syncthreads();
#pragma unroll
    for (int kc = 0; kc < 4; ++kc) {
      const int mb = mh2 * 128 + kc * 32 + koff;
      const int ca = mb ^ ((r & 31) << 3);
      short8v qh8 = *(const short8v*)&qph[r][ca];
#pragma unroll
      for (int et = 0; et < 2; ++et) {
        const int erow = (ms * 2 + et) * 16 + llo;
        const int cb = sw16(erow, kc * 32 + koff);
        short8v th = *(const short8v*)&ctTh[erow][cb];
        short8v tl = *(const short8v*)&ctTl[erow][cb];
        oacc[et] = MFMA16(qh8, th, oacc[et]);
        oacc[et] = MFMA16(qh8, tl, oacc[et]);
      }
    }
  }

  // epilogue
  float inv[4];
#pragma unroll
  for (int jj = 0; jj < 4; ++jj) inv[jj] = 1.0f / denL[rt * 16 + lhi * 4 + jj];
#pragma unroll
  for (int et = 0; et < 2; ++et)
#pragma unroll
    for (int jj = 0; jj < 4; ++jj) {
      const int ro = rt * 16 + lhi * 4 + jj;
      const int e2 = (ms * 2 + et) * 16 + llo;
      out[((size_t)bh * Nn + rb * 64 + ro) * 64 + e2] = oacc[et][jj] * inv[jj];
    }
}

extern "C" void kernel_launch(void* const* d_in, const int* in_sizes, int n_in,
                              void* d_out, int out_size, void* d_ws, size_t ws_size,
                              hipStream_t stream) {
  const float* q = (const float*)d_in[0];
  const float* k = (const float*)d_in[1];
  const float* v = (const float*)d_in[2];
  const float* proj = (const float*)d_in[3];
  float* outp = (float*)d_out;

  char* ws = (char*)d_ws;
  unsigned* stabKey = (unsigned*)(ws + oStab);
  float* EsumG = (float*)(ws + oEsum);
  float* VsumG = (float*)(ws + oVsum);
  float* kshatG = (float*)(ws + oKshat);
  float* ctxEG = (float*)(ws + oCtxE);
  short* ctHG = (short*)(ws + oCtH);
  short* ctLG = (short*)(ws + oCtL);
  short* PhG = (short*)(ws + oPh);
  short* PlG = (short*)(ws + oPl);

  hipMemsetAsync(d_ws, 0, kZeroBytes, stream);
  perf_prep<<<16, 256, 0, stream>>>(proj, PhG, PlG);
  perf_kside<<<dim3(BHn, 16), 512, 0, stream>>>(k, v, PhG, PlG, stabKey, EsumG, VsumG, ctxEG);
  perf_combine<<<BHn, 256, 0, stream>>>(stabKey, EsumG, VsumG, ctxEG, kshatG, ctHG, ctLG);
  perf_qside<<<dim3(BHn, 64), 512, 0, stream>>>(q, PhG, PlG, kshatG, ctHG, ctLG, outp);
}

// Round 9
// 305.860 us; speedup vs baseline: 1.2621x; 1.2621x over previous
//
#include <hip/hip_runtime.h>
#include <hip/hip_bf16.h>
#include <float.h>

// Performer FastAttention (FAVOR+), MFMA bf16-split v4.2.
// Round 9: round-7 structure with __launch_bounds__(512, 2) (round-6's
// working setting). (512,4)/waves_per_eu(4,4) made the allocator clamp to
// 64 VGPRs and spill ~280MB/dispatch of scratch traffic (r7/r8 counters).

typedef __attribute__((ext_vector_type(8))) short short8v;
typedef __attribute__((ext_vector_type(4))) short short4v;
typedef __attribute__((ext_vector_type(4))) float f32x4;

#define MFMA16(a, b, c) __builtin_amdgcn_mfma_f32_16x16x32_bf16(a, b, c, 0, 0, 0)

namespace {
constexpr int Nn = 4096, Dd = 64, BHn = 96;
constexpr float kNorm = 0.35355339059327379f;  // 64^-0.25
constexpr float kDiagCoef = 0.0625f;           // 0.5 * 64^-0.5
constexpr float kEps = 1e-4f;

constexpr size_t oStab  = 0;                                   // 96 u32
constexpr size_t oEsum  = 512;                                 // 96*256 f32
constexpr size_t oVsum  = oEsum + (size_t)BHn * 256 * 4;       // 96*64 f32
constexpr size_t oKshat = oVsum + (size_t)BHn * 64 * 4;        // 96*256 f32
constexpr size_t oCtxE  = oKshat + (size_t)BHn * 256 * 4;      // 96*256*64 f32
constexpr size_t oCtH   = oCtxE + (size_t)BHn * 256 * 64 * 4;  // 96*64*256 bf16
constexpr size_t oCtL   = oCtH + (size_t)BHn * 64 * 256 * 2;
constexpr size_t oPh    = oCtL + (size_t)BHn * 64 * 256 * 2;   // 256*64 bf16
constexpr size_t oPl    = oPh + (size_t)256 * 64 * 2;
constexpr size_t kZeroBytes = oCtH;  // zero stab..ctxE accumulators
}

static __device__ __forceinline__ unsigned floatKey(float f) {
  unsigned b = __float_as_uint(f);
  return (b & 0x80000000u) ? ~b : (b | 0x80000000u);
}
static __device__ __forceinline__ float keyToFloat(unsigned k) {
  unsigned b = (k & 0x80000000u) ? (k & 0x7fffffffu) : ~k;
  return __uint_as_float(b);
}
static __device__ __forceinline__ short f2bf(float x) {
  union { __hip_bfloat16 h; short s; } u;
  u.h = __float2bfloat16(x);
  return u.s;
}
static __device__ __forceinline__ float bf2f(short s) {
  return __uint_as_float(((unsigned)(unsigned short)s) << 16);
}
static __device__ __forceinline__ void splitbf(float x, short& h, short& l) {
  h = f2bf(x);
  l = f2bf(x - bf2f(h));
}
static __device__ __forceinline__ int sw8(int row, int col)  { return col ^ ((row & 7) << 3); }
static __device__ __forceinline__ int sw16(int row, int col) { return col ^ ((row & 15) << 3); }

// ---------------------------------------------------------------------------
// prep: split proj into bf16 hi/lo, linear [m][d] layout in ws.
// ---------------------------------------------------------------------------
__global__ void perf_prep(const float* __restrict__ proj, short* __restrict__ Ph,
                          short* __restrict__ Pl) {
  const int i = (blockIdx.x * 256 + threadIdx.x) * 4;  // 16384 elems
  float4 v = *(const float4*)(proj + i);
  float xs[4] = {v.x, v.y, v.z, v.w};
  short4v h, l;
#pragma unroll
  for (int j = 0; j < 4; ++j) {
    short hh, ll;
    splitbf(xs[j], hh, ll);
    h[j] = hh;
    l[j] = ll;
  }
  *(short4v*)(Ph + i) = h;
  *(short4v*)(Pl + i) = l;
}

// ---------------------------------------------------------------------------
// kside: grid (96, 16), block 512 (8 waves). 256 k-rows/block, 4 subs of 64.
// Wave w owns m-strip w*32..+32. proj frags in regs; dd -> E -> ctx all
// wave-local via private scratch (swizzled). 2 barriers per sub.
// ---------------------------------------------------------------------------
__global__ __launch_bounds__(512, 2) void perf_kside(
    const float* __restrict__ K, const float* __restrict__ V,
    const short* __restrict__ PhG, const short* __restrict__ PlG,
    unsigned* __restrict__ stabKey, float* __restrict__ EsumG,
    float* __restrict__ VsumG, float* __restrict__ ctxEG) {
  const int t = threadIdx.x, bh = blockIdx.x, chunk = blockIdx.y;
  const int w = t >> 6, l = t & 63;
  const int lhi = l >> 4, llo = l & 15;
  const int koff = lhi * 8;

  __shared__ short Kh[64][64], Kl[64][64];
  __shared__ short Vh[64][64], Vl[64][64];      // V^T: [e][n]
  __shared__ short EsH[8][16][64], EsL[8][16][64];  // wave-private E^T scratch
  __shared__ float diag[64];
  __shared__ float rpartV[8][64];
  __shared__ float wpmax[8];

  // proj fragments in registers (wave's 32-m strip, both kb slices, hi+lo)
  short8v prh[2][2], prl[2][2];
#pragma unroll
  for (int mt = 0; mt < 2; ++mt)
#pragma unroll
    for (int kb = 0; kb < 2; ++kb) {
      const int m = w * 32 + mt * 16 + llo;
      prh[mt][kb] = *(const short8v*)(PhG + m * 64 + kb * 32 + koff);
      prl[mt][kb] = *(const short8v*)(PlG + m * 64 + kb * 32 + koff);
    }

  float mx = -FLT_MAX, vsum_r = 0.f;
  f32x4 cacc[2][4];
  float es[2] = {0.f, 0.f};
#pragma unroll
  for (int a = 0; a < 2; ++a)
#pragma unroll
    for (int b = 0; b < 4; ++b) cacc[a][b] = f32x4{0.f, 0.f, 0.f, 0.f};

  char* esh = (char*)&EsH[w][0][0] + llo * 128;
  char* esl = (char*)&EsL[w][0][0] + llo * 128;
  const int swz = (llo & 7) << 4;

  const size_t base = ((size_t)bh * Nn + chunk * 256) * Dd;

  for (int sub = 0; sub < 4; ++sub) {
    __syncthreads();  // prev sub's consumers done with Kh/Vh
    {  // stage K rows (split + diag partial), coalesced
      const int n = t >> 3, d0 = (t & 7) * 8;
      const float* ks = K + base + (size_t)(sub * 64 + n) * 64 + d0;
      const float4 a = *(const float4*)ks;
      const float4 b = *(const float4*)(ks + 4);
      float xs[8] = {a.x, a.y, a.z, a.w, b.x, b.y, b.z, b.w};
      float s = 0.f;
#pragma unroll
      for (int i = 0; i < 8; ++i) s = fmaf(xs[i], xs[i], s);
      s += __shfl_xor(s, 1); s += __shfl_xor(s, 2); s += __shfl_xor(s, 4);
      if ((t & 7) == 0) diag[n] = s * kDiagCoef;
      short8v h8, l8;
#pragma unroll
      for (int i = 0; i < 8; ++i) {
        short hh, ll;
        splitbf(kNorm * xs[i], hh, ll);
        h8[i] = hh; l8[i] = ll;
      }
      const int c = sw8(n, d0);
      *(short8v*)&Kh[n][c] = h8;
      *(short8v*)&Kl[n][c] = l8;
    }
    {  // stage V^T by transposed-coalesced global reads (+vsum)
      const int e = l, n0 = w * 8;
      const float* vs = V + base + (size_t)(sub * 64 + n0) * 64 + e;
      short8v h8, l8;
#pragma unroll
      for (int i = 0; i < 8; ++i) {
        float xv = vs[i * 64];
        vsum_r += xv;
        short hh, ll;
        splitbf(xv, hh, ll);
        h8[i] = hh; l8[i] = ll;
      }
      const int c = sw8(e, n0);
      *(short8v*)&Vh[e][c] = h8;
      *(short8v*)&Vl[e][c] = l8;
    }
    __syncthreads();  // tiles ready

#pragma unroll
    for (int mt = 0; mt < 2; ++mt) {
      float esa = 0.f;
#pragma unroll
      for (int b = 0; b < 4; ++b) {
        const int arow = b * 16 + llo;
        f32x4 acc = f32x4{0.f, 0.f, 0.f, 0.f};
#pragma unroll
        for (int kb = 0; kb < 2; ++kb) {
          const int c = sw8(arow, kb * 32 + koff);
          short8v ah = *(const short8v*)&Kh[arow][c];
          short8v al = *(const short8v*)&Kl[arow][c];
          acc = MFMA16(ah, prh[mt][kb], acc);
          acc = MFMA16(ah, prl[mt][kb], acc);
          acc = MFMA16(al, prh[mt][kb], acc);
        }
        // lane holds dd[n = b*16 + lhi*4 + jj][m = w*32 + mt*16 + llo]
        unsigned wH[2], wL[2];
#pragma unroll
        for (int q = 0; q < 2; ++q) {
          short h0, l0, h1, l1;
          float dd0 = acc[2 * q + 0];
          float dd1 = acc[2 * q + 1];
          mx = fmaxf(mx, fmaxf(dd0, dd1));
          float E0 = __expf(dd0 - diag[b * 16 + lhi * 4 + 2 * q + 0]);
          float E1 = __expf(dd1 - diag[b * 16 + lhi * 4 + 2 * q + 1]);
          esa += E0 + E1;
          splitbf(E0, h0, l0);
          splitbf(E1, h1, l1);
          wH[q] = (unsigned)(unsigned short)h0 | ((unsigned)(unsigned short)h1 << 16);
          wL[q] = (unsigned)(unsigned short)l0 | ((unsigned)(unsigned short)l1 << 16);
        }
        const int off = (b * 32 + lhi * 8) ^ swz;
        uint2 uh; uh.x = wH[0]; uh.y = wH[1];
        uint2 ul; ul.x = wL[0]; ul.y = wL[1];
        *(uint2*)(esh + off) = uh;
        *(uint2*)(esl + off) = ul;
      }
      es[mt] += esa;
      // ctx GEMM: A = E^T from private scratch, B = V^T from LDS
#pragma unroll
      for (int s = 0; s < 2; ++s) {
        const int roff = (s * 64 + lhi * 16) ^ swz;
        short8v ah8 = *(const short8v*)(esh + roff);
        short8v al8 = *(const short8v*)(esl + roff);
#pragma unroll
        for (int et = 0; et < 4; ++et) {
          const int ecol = et * 16 + llo;
          const int c = sw8(ecol, s * 32 + koff);
          short8v vh8 = *(const short8v*)&Vh[ecol][c];
          short8v vl8 = *(const short8v*)&Vl[ecol][c];
          f32x4 a2 = cacc[mt][et];
          a2 = MFMA16(ah8, vh8, a2);
          a2 = MFMA16(ah8, vl8, a2);
          a2 = MFMA16(al8, vh8, a2);
          cacc[mt][et] = a2;
        }
      }
    }
  }

  // reductions
#pragma unroll
  for (int off = 32; off; off >>= 1) mx = fmaxf(mx, __shfl_xor(mx, off));
  if (l == 0) wpmax[w] = mx;
#pragma unroll
  for (int mt = 0; mt < 2; ++mt) {
    float v2 = es[mt];
    v2 += __shfl_xor(v2, 16);
    v2 += __shfl_xor(v2, 32);
    if (l < 16) atomicAdd(&EsumG[bh * 256 + w * 32 + mt * 16 + l], v2);
  }
  rpartV[w][l] = vsum_r;
  __syncthreads();
  if (t < 64) {
    float s2 = 0.f;
#pragma unroll
    for (int w2 = 0; w2 < 8; ++w2) s2 += rpartV[w2][t];
    atomicAdd(&VsumG[bh * 64 + t], s2);
  }
  if (t == 0) {
    float b = wpmax[0];
#pragma unroll
    for (int w2 = 1; w2 < 8; ++w2) b = fmaxf(b, wpmax[w2]);
    atomicMax(stabKey + bh, floatKey(b));
  }
#pragma unroll
  for (int mt = 0; mt < 2; ++mt)
#pragma unroll
    for (int et = 0; et < 4; ++et)
#pragma unroll
      for (int jj = 0; jj < 4; ++jj) {
        const int m2 = w * 32 + mt * 16 + lhi * 4 + jj;
        const int e2 = et * 16 + llo;
        atomicAdd(&ctxEG[((size_t)bh * 256 + m2) * 64 + e2], cacc[mt][et][jj]);
      }
}

// ---------------------------------------------------------------------------
// combine: kshat[m] = e^{-stab}*Esum + eps*N; ctxhat -> transposed bf16 pair.
// ---------------------------------------------------------------------------
__global__ __launch_bounds__(256) void perf_combine(
    const unsigned* __restrict__ stabKey, const float* __restrict__ EsumG,
    const float* __restrict__ VsumG, const float* __restrict__ ctxEG,
    float* __restrict__ kshatG, short* __restrict__ ctHG, short* __restrict__ ctLG) {
  const int bh = blockIdx.x, t = threadIdx.x;
  const float esc = __expf(-keyToFloat(stabKey[bh]));
  kshatG[bh * 256 + t] = esc * EsumG[bh * 256 + t] + kEps * 4096.0f;
  for (int e = 0; e < 64; ++e) {
    const float v2 = esc * ctxEG[((size_t)bh * 256 + t) * 64 + e] + kEps * VsumG[bh * 64 + e];
    short hh, ll;
    splitbf(v2, hh, ll);
    ctHG[((size_t)bh * 64 + e) * 256 + t] = hh;
    ctLG[((size_t)bh * 64 + e) * 256 + t] = ll;
  }
}

// ---------------------------------------------------------------------------
// qside: grid (96, 64), block 512. 64 q-rows/block. LDS 65.5K.
// proj staged per-128-half (32K, reused as ctT); dd 2 phases; q' hi-only with
// den from same rounded weights; out GEMM 2-term.
// ---------------------------------------------------------------------------
__global__ __launch_bounds__(512, 2) void perf_qside(
    const float* __restrict__ Q, const short* __restrict__ PhG,
    const short* __restrict__ PlG, const float* __restrict__ kshatG,
    const short* __restrict__ ctHG, const short* __restrict__ ctLG,
    float* __restrict__ out) {
  const int t = threadIdx.x, bh = blockIdx.x, rb = blockIdx.y;
  const int w = t >> 6, l = t & 63;
  const int rt = w & 3, ms = w >> 2;
  const int lhi = l >> 4, llo = l & 15;
  const int koff = lhi * 8;

  __shared__ short Ph[128][64], Pl[128][64];  // per-phase proj; reused as ctT[64][128]
  __shared__ short qph[64][256];              // q' bf16 (hi only)
  __shared__ float kshatL[256];
  __shared__ unsigned rmaxKey[64];
  __shared__ float denL[64];

  if (t < 64) { rmaxKey[t] = 0u; denL[t] = 0.f; }
  if (t < 256) kshatL[t] = kshatG[bh * 256 + t];

  const int r = rt * 16 + llo;  // this lane's q-row

  // Q fragments + diag (global direct; folded norm)
  short8v qh[2], ql[2];
  float dgq;
  {
    const float* qs = Q + ((size_t)bh * Nn + rb * 64 + r) * 64 + koff;
    float4 a0 = *(const float4*)qs;
    float4 a1 = *(const float4*)(qs + 4);
    float4 b0 = *(const float4*)(qs + 32);
    float4 b1 = *(const float4*)(qs + 36);
    float xs[16] = {a0.x, a0.y, a0.z, a0.w, a1.x, a1.y, a1.z, a1.w,
                    b0.x, b0.y, b0.z, b0.w, b1.x, b1.y, b1.z, b1.w};
    float s = 0.f;
#pragma unroll
    for (int i = 0; i < 16; ++i) s = fmaf(xs[i], xs[i], s);
    s += __shfl_xor(s, 16);
    s += __shfl_xor(s, 32);
    dgq = s * kDiagCoef;
#pragma unroll
    for (int kb = 0; kb < 2; ++kb) {
      short8v h8, l8;
#pragma unroll
      for (int i = 0; i < 8; ++i) {
        short hh, ll;
        splitbf(kNorm * xs[kb * 8 + i], hh, ll);
        h8[i] = hh; l8[i] = ll;
      }
      qh[kb] = h8; ql[kb] = l8;
    }
  }

  // dd GEMM in 2 phases of 128 m (proj half staged per phase)
  f32x4 dacc[8];
#pragma unroll
  for (int ph = 0; ph < 2; ++ph) {
    __syncthreads();  // init / prev-phase dd reads done
    {  // stage proj half ph
      const int i = t >> 2, d0 = (t & 3) * 16;
      const short* gh = PhG + (ph * 128 + i) * 64 + d0;
      const short* gl = PlG + (ph * 128 + i) * 64 + d0;
      const int c0 = sw8(i, d0), c1 = sw8(i, d0 + 8);
      *(short8v*)&Ph[i][c0] = *(const short8v*)gh;
      *(short8v*)&Ph[i][c1] = *(const short8v*)(gh + 8);
      *(short8v*)&Pl[i][c0] = *(const short8v*)gl;
      *(short8v*)&Pl[i][c1] = *(const short8v*)(gl + 8);
    }
    __syncthreads();
#pragma unroll
    for (int mt = 0; mt < 4; ++mt) {
      const int mrow = ms * 64 + mt * 16 + llo;
      f32x4 acc = f32x4{0.f, 0.f, 0.f, 0.f};
#pragma unroll
      for (int kb = 0; kb < 2; ++kb) {
        const int c = sw8(mrow, kb * 32 + koff);
        short8v pbh = *(const short8v*)&Ph[mrow][c];
        short8v pbl = *(const short8v*)&Pl[mrow][c];
        acc = MFMA16(pbh, qh[kb], acc);
        acc = MFMA16(pbh, ql[kb], acc);
        acc = MFMA16(pbl, qh[kb], acc);
      }
      dacc[ph * 4 + mt] = acc;  // dd[m = ph*128+ms*64+mt*16+lhi*4+jj][r]
    }
  }

  // rowmax over this wave's 128 m's, merged across ms pair via LDS
  {
    float mx = dacc[0][0];
#pragma unroll
    for (int i = 0; i < 8; ++i)
#pragma unroll
      for (int jj = 0; jj < 4; ++jj) mx = fmaxf(mx, dacc[i][jj]);
    mx = fmaxf(mx, __shfl_xor(mx, 16));
    mx = fmaxf(mx, __shfl_xor(mx, 32));
    if (l < 16) atomicMax(&rmaxKey[rt * 16 + l], floatKey(mx));
  }
  __syncthreads();

  // exp -> q' (bf16 hi), den from the SAME rounded weights
  {
    const float shift = dgq + keyToFloat(rmaxKey[r]);
    float den = 0.f;
#pragma unroll
    for (int i = 0; i < 8; ++i) {
      const int m0 = (i >> 2) * 128 + ms * 64 + (i & 3) * 16 + lhi * 4;
      const f32x4 ksv = *(const f32x4*)&kshatL[m0];
      short4v h4;
#pragma unroll
      for (int jj = 0; jj < 4; ++jj) {
        float qv = __expf(dacc[i][jj] - shift) + kEps;
        short hh = f2bf(qv);
        h4[jj] = hh;
        den = fmaf(bf2f(hh), ksv[jj], den);  // consistent with numerator
      }
      const int c = m0 ^ ((r & 31) << 3);
      *(short4v*)&qph[r][c] = h4;
    }
    den += __shfl_xor(den, 16);
    den += __shfl_xor(den, 32);
    if (l < 16) atomicAdd(&denL[rt * 16 + l], den);
  }

  // output GEMM: ctT staged per m-half into reused Ph/Pl space; 2-term
  short(*ctTh)[128] = (short(*)[128])Ph;
  short(*ctTl)[128] = (short(*)[128])Pl;
  f32x4 oacc[2] = {f32x4{0.f, 0.f, 0.f, 0.f}, f32x4{0.f, 0.f, 0.f, 0.f}};
#pragma unroll
  for (int mh2 = 0; mh2 < 2; ++mh2) {
    __syncthreads();  // qp/den writes done (mh2=0) / prev MFMAs done (mh2=1)
    {  // stage ctxhatT half
      const int e = t >> 3, mg = t & 7;
      const short* gh = ctHG + ((size_t)bh * 64 + e) * 256 + mh2 * 128 + mg * 16;
      const short* gl = ctLG + ((size_t)bh * 64 + e) * 256 + mh2 * 128 + mg * 16;
      short8v a0 = *(const short8v*)gh;
      short8v a1 = *(const short8v*)(gh + 8);
      short8v b0 = *(const short8v*)gl;
      short8v b1 = *(const short8v*)(gl + 8);
      *(short8v*)&ctTh[e][sw16(e, mg * 16)] = a0;
      *(short8v*)&ctTh[e][sw16(e, mg * 16 + 8)] = a1;
      *(short8v*)&ctTl[e][sw16(e, mg * 16)] = b0;
      *(short8v*)&ctTl[e][sw16(e, mg * 16 + 8)] = b1;
    }
    __syncthreads();
#pragma unroll
    for (int kc = 0; kc < 4; ++kc) {
      const int mb = mh2 * 128 + kc * 32 + koff;
      const int ca = mb ^ ((r & 31) << 3);
      short8v qh8 = *(const short8v*)&qph[r][ca];
#pragma unroll
      for (int et = 0; et < 2; ++et) {
        const int erow = (ms * 2 + et) * 16 + llo;
        const int cb = sw16(erow, kc * 32 + koff);
        short8v th = *(const short8v*)&ctTh[erow][cb];
        short8v tl = *(const short8v*)&ctTl[erow][cb];
        oacc[et] = MFMA16(qh8, th, oacc[et]);
        oacc[et] = MFMA16(qh8, tl, oacc[et]);
      }
    }
  }

  // epilogue
  float inv[4];
#pragma unroll
  for (int jj = 0; jj < 4; ++jj) inv[jj] = 1.0f / denL[rt * 16 + lhi * 4 + jj];
#pragma unroll
  for (int et = 0; et < 2; ++et)
#pragma unroll
    for (int jj = 0; jj < 4; ++jj) {
      const int ro = rt * 16 + lhi * 4 + jj;
      const int e2 = (ms * 2 + et) * 16 + llo;
      out[((size_t)bh * Nn + rb * 64 + ro) * 64 + e2] = oacc[et][jj] * inv[jj];
    }
}

extern "C" void kernel_launch(void* const* d_in, const int* in_sizes, int n_in,
                              void* d_out, int out_size, void* d_ws, size_t ws_size,
                              hipStream_t stream) {
  const float* q = (const float*)d_in[0];
  const float* k = (const float*)d_in[1];
  const float* v = (const float*)d_in[2];
  const float* proj = (const float*)d_in[3];
  float* outp = (float*)d_out;

  char* ws = (char*)d_ws;
  unsigned* stabKey = (unsigned*)(ws + oStab);
  float* EsumG = (float*)(ws + oEsum);
  float* VsumG = (float*)(ws + oVsum);
  float* kshatG = (float*)(ws + oKshat);
  float* ctxEG = (float*)(ws + oCtxE);
  short* ctHG = (short*)(ws + oCtH);
  short* ctLG = (short*)(ws + oCtL);
  short* PhG = (short*)(ws + oPh);
  short* PlG = (short*)(ws + oPl);

  hipMemsetAsync(d_ws, 0, kZeroBytes, stream);
  perf_prep<<<16, 256, 0, stream>>>(proj, PhG, PlG);
  perf_kside<<<dim3(BHn, 16), 512, 0, stream>>>(k, v, PhG, PlG, stabKey, EsumG, VsumG, ctxEG);
  perf_combine<<<BHn, 256, 0, stream>>>(stabKey, EsumG, VsumG, ctxEG, kshatG, ctHG, ctLG);
  perf_qside<<<dim3(BHn, 64), 512, 0, stream>>>(q, PhG, PlG, kshatG, ctHG, ctLG, outp);
}

// Round 10
// 293.523 us; speedup vs baseline: 1.3152x; 1.0420x over previous
//
#include <hip/hip_runtime.h>
#include <hip/hip_bf16.h>
#include <float.h>

// Performer FastAttention (FAVOR+), MFMA bf16-split v5.
// Round 10: kside ctx GEMM switched to 16x16x16 MFMA consuming the exp'd dd
// accumulator directly as A-fragment (registers) -- E never touches LDS.
// LDS instr/sub/wave ~124 -> ~57; kside LDS 68 -> 35 KB. qside unchanged.

typedef __attribute__((ext_vector_type(8))) short short8v;
typedef __attribute__((ext_vector_type(4))) short short4v;
typedef __attribute__((ext_vector_type(4))) float f32x4;

#define MFMA32(a, b, c) __builtin_amdgcn_mfma_f32_16x16x32_bf16(a, b, c, 0, 0, 0)

#if defined(__has_builtin)
#if __has_builtin(__builtin_amdgcn_mfma_f32_16x16x16bf16_1k)
#define HAVE_MFMA16_1K 1
#endif
#endif
#ifdef HAVE_MFMA16_1K
#define MFMA16K(a, b, c) __builtin_amdgcn_mfma_f32_16x16x16bf16_1k(a, b, c, 0, 0, 0)
#else
static __device__ __forceinline__ f32x4 mfma16k_asm(short4v a, short4v b, f32x4 c) {
  asm("s_nop 1\n\tv_mfma_f32_16x16x16_bf16 %0, %1, %2, %0" : "+v"(c) : "v"(a), "v"(b));
  return c;
}
#define MFMA16K(a, b, c) mfma16k_asm(a, b, c)
#endif

namespace {
constexpr int Nn = 4096, Dd = 64, BHn = 96;
constexpr float kNorm = 0.35355339059327379f;  // 64^-0.25
constexpr float kDiagCoef = 0.0625f;           // 0.5 * 64^-0.5
constexpr float kEps = 1e-4f;

constexpr size_t oStab  = 0;                                   // 96 u32
constexpr size_t oEsum  = 512;                                 // 96*256 f32
constexpr size_t oVsum  = oEsum + (size_t)BHn * 256 * 4;       // 96*64 f32
constexpr size_t oKshat = oVsum + (size_t)BHn * 64 * 4;        // 96*256 f32
constexpr size_t oCtxE  = oKshat + (size_t)BHn * 256 * 4;      // 96*256*64 f32
constexpr size_t oCtH   = oCtxE + (size_t)BHn * 256 * 64 * 4;  // 96*64*256 bf16
constexpr size_t oCtL   = oCtH + (size_t)BHn * 64 * 256 * 2;
constexpr size_t oPh    = oCtL + (size_t)BHn * 64 * 256 * 2;   // 256*64 bf16
constexpr size_t oPl    = oPh + (size_t)256 * 64 * 2;
constexpr size_t kZeroBytes = oCtH;  // zero stab..ctxE accumulators
}

static __device__ __forceinline__ unsigned floatKey(float f) {
  unsigned b = __float_as_uint(f);
  return (b & 0x80000000u) ? ~b : (b | 0x80000000u);
}
static __device__ __forceinline__ float keyToFloat(unsigned k) {
  unsigned b = (k & 0x80000000u) ? (k & 0x7fffffffu) : ~k;
  return __uint_as_float(b);
}
static __device__ __forceinline__ short f2bf(float x) {
  union { __hip_bfloat16 h; short s; } u;
  u.h = __float2bfloat16(x);
  return u.s;
}
static __device__ __forceinline__ float bf2f(short s) {
  return __uint_as_float(((unsigned)(unsigned short)s) << 16);
}
static __device__ __forceinline__ void splitbf(float x, short& h, short& l) {
  h = f2bf(x);
  l = f2bf(x - bf2f(h));
}
static __device__ __forceinline__ int sw8(int row, int col)  { return col ^ ((row & 7) << 3); }
static __device__ __forceinline__ int sw16(int row, int col) { return col ^ ((row & 15) << 3); }

// ---------------------------------------------------------------------------
// prep: split proj into bf16 hi/lo, linear [m][d] layout in ws.
// ---------------------------------------------------------------------------
__global__ void perf_prep(const float* __restrict__ proj, short* __restrict__ Ph,
                          short* __restrict__ Pl) {
  const int i = (blockIdx.x * 256 + threadIdx.x) * 4;  // 16384 elems
  float4 v = *(const float4*)(proj + i);
  float xs[4] = {v.x, v.y, v.z, v.w};
  short4v h, l;
#pragma unroll
  for (int j = 0; j < 4; ++j) {
    short hh, ll;
    splitbf(xs[j], hh, ll);
    h[j] = hh;
    l[j] = ll;
  }
  *(short4v*)(Ph + i) = h;
  *(short4v*)(Pl + i) = l;
}

// ---------------------------------------------------------------------------
// kside: grid (96, 16), block 512 (8 waves). 256 k-rows/block, 4 subs of 64.
// Wave w owns m-strip w*32..+32 (proj frags in regs). Per b-tile (16 n):
// dd via 16x16x32 MFMA; exp'd accumulator feeds ctx 16x16x16 MFMAs directly
// (A = E^T from regs, B = V^T from LDS b64 frags). No E scratch, no extra
// barriers. LDS ~35 KB.
// ---------------------------------------------------------------------------
__global__ __launch_bounds__(512, 2) void perf_kside(
    const float* __restrict__ K, const float* __restrict__ V,
    const short* __restrict__ PhG, const short* __restrict__ PlG,
    unsigned* __restrict__ stabKey, float* __restrict__ EsumG,
    float* __restrict__ VsumG, float* __restrict__ ctxEG) {
  const int t = threadIdx.x, bh = blockIdx.x, chunk = blockIdx.y;
  const int w = t >> 6, l = t & 63;
  const int lhi = l >> 4, llo = l & 15;
  const int koff = lhi * 8;

  __shared__ short Kh[64][64], Kl[64][64];
  __shared__ short Vh[64][64], Vl[64][64];      // V^T: [e][n]
  __shared__ float diag[64];
  __shared__ float rpartV[8][64];
  __shared__ float wpmax[8];

  // proj fragments in registers (wave's 32-m strip, both kb slices, hi+lo)
  short8v prh[2][2], prl[2][2];
#pragma unroll
  for (int mt = 0; mt < 2; ++mt)
#pragma unroll
    for (int kb = 0; kb < 2; ++kb) {
      const int m = w * 32 + mt * 16 + llo;
      prh[mt][kb] = *(const short8v*)(PhG + m * 64 + kb * 32 + koff);
      prl[mt][kb] = *(const short8v*)(PlG + m * 64 + kb * 32 + koff);
    }

  float mx = -FLT_MAX, vsum_r = 0.f;
  f32x4 cacc[2][4];
  float es[2] = {0.f, 0.f};
#pragma unroll
  for (int a = 0; a < 2; ++a)
#pragma unroll
    for (int b = 0; b < 4; ++b) cacc[a][b] = f32x4{0.f, 0.f, 0.f, 0.f};

  const size_t base = ((size_t)bh * Nn + chunk * 256) * Dd;

  for (int sub = 0; sub < 4; ++sub) {
    __syncthreads();  // prev sub's consumers done with Kh/Vh
    {  // stage K rows (split + diag partial), coalesced
      const int n = t >> 3, d0 = (t & 7) * 8;
      const float* ks = K + base + (size_t)(sub * 64 + n) * 64 + d0;
      const float4 a = *(const float4*)ks;
      const float4 b = *(const float4*)(ks + 4);
      float xs[8] = {a.x, a.y, a.z, a.w, b.x, b.y, b.z, b.w};
      float s = 0.f;
#pragma unroll
      for (int i = 0; i < 8; ++i) s = fmaf(xs[i], xs[i], s);
      s += __shfl_xor(s, 1); s += __shfl_xor(s, 2); s += __shfl_xor(s, 4);
      if ((t & 7) == 0) diag[n] = s * kDiagCoef;
      short8v h8, l8;
#pragma unroll
      for (int i = 0; i < 8; ++i) {
        short hh, ll;
        splitbf(kNorm * xs[i], hh, ll);
        h8[i] = hh; l8[i] = ll;
      }
      const int c = sw8(n, d0);
      *(short8v*)&Kh[n][c] = h8;
      *(short8v*)&Kl[n][c] = l8;
    }
    {  // stage V^T by transposed-coalesced global reads (+vsum)
      const int e = l, n0 = w * 8;
      const float* vs = V + base + (size_t)(sub * 64 + n0) * 64 + e;
      short8v h8, l8;
#pragma unroll
      for (int i = 0; i < 8; ++i) {
        float xv = vs[i * 64];
        vsum_r += xv;
        short hh, ll;
        splitbf(xv, hh, ll);
        h8[i] = hh; l8[i] = ll;
      }
      const int c = sw8(e, n0);
      *(short8v*)&Vh[e][c] = h8;
      *(short8v*)&Vl[e][c] = l8;
    }
    __syncthreads();  // tiles ready

#pragma unroll
    for (int b = 0; b < 4; ++b) {
      // K fragments for this n-tile
      const int arow = b * 16 + llo;
      short8v kh[2], kl[2];
#pragma unroll
      for (int kb = 0; kb < 2; ++kb) {
        const int c = sw8(arow, kb * 32 + koff);
        kh[kb] = *(const short8v*)&Kh[arow][c];
        kl[kb] = *(const short8v*)&Kl[arow][c];
      }
      // V^T b64 fragments for K=16 MFMA (rows e, k = b*16 + lhi*4..+4)
      short4v vh[4], vl[4];
#pragma unroll
      for (int et = 0; et < 4; ++et) {
        const int ecol = et * 16 + llo;
        const int cc = sw8(ecol, b * 16 + lhi * 4);
        vh[et] = *(const short4v*)&Vh[ecol][cc];
        vl[et] = *(const short4v*)&Vl[ecol][cc];
      }
      const f32x4 dg = *(const f32x4*)&diag[b * 16 + lhi * 4];

#pragma unroll
      for (int mt = 0; mt < 2; ++mt) {
        // dd GEMM (16x16x32, 3-term): lane holds dd[n=b*16+lhi*4+jj][m=..llo]
        f32x4 acc = f32x4{0.f, 0.f, 0.f, 0.f};
#pragma unroll
        for (int kb = 0; kb < 2; ++kb) {
          acc = MFMA32(kh[kb], prh[mt][kb], acc);
          acc = MFMA32(kh[kb], prl[mt][kb], acc);
          acc = MFMA32(kl[kb], prh[mt][kb], acc);
        }
        // exp -> E fragment (A-operand of 16x16x16: A[m=llo][k=lhi*4+jj])
        short4v h4, l4;
        float esa = 0.f;
#pragma unroll
        for (int jj = 0; jj < 4; ++jj) {
          float dd = acc[jj];
          mx = fmaxf(mx, dd);
          float E = __expf(dd - dg[jj]);
          esa += E;
          short hh, ll;
          splitbf(E, hh, ll);
          h4[jj] = hh; l4[jj] = ll;
        }
        es[mt] += esa;
        // ctx GEMM (16x16x16, 3-term): cacc[m-row][e-col] += E^T . V^T
#pragma unroll
        for (int et = 0; et < 4; ++et) {
          f32x4 a2 = cacc[mt][et];
          a2 = MFMA16K(h4, vh[et], a2);
          a2 = MFMA16K(h4, vl[et], a2);
          a2 = MFMA16K(l4, vh[et], a2);
          cacc[mt][et] = a2;
        }
      }
    }
  }

  // reductions
#pragma unroll
  for (int off = 32; off; off >>= 1) mx = fmaxf(mx, __shfl_xor(mx, off));
  if (l == 0) wpmax[w] = mx;
#pragma unroll
  for (int mt = 0; mt < 2; ++mt) {
    float v2 = es[mt];
    v2 += __shfl_xor(v2, 16);
    v2 += __shfl_xor(v2, 32);
    if (l < 16) atomicAdd(&EsumG[bh * 256 + w * 32 + mt * 16 + l], v2);
  }
  rpartV[w][l] = vsum_r;
  __syncthreads();
  if (t < 64) {
    float s2 = 0.f;
#pragma unroll
    for (int w2 = 0; w2 < 8; ++w2) s2 += rpartV[w2][t];
    atomicAdd(&VsumG[bh * 64 + t], s2);
  }
  if (t == 0) {
    float b = wpmax[0];
#pragma unroll
    for (int w2 = 1; w2 < 8; ++w2) b = fmaxf(b, wpmax[w2]);
    atomicMax(stabKey + bh, floatKey(b));
  }
#pragma unroll
  for (int mt = 0; mt < 2; ++mt)
#pragma unroll
    for (int et = 0; et < 4; ++et)
#pragma unroll
      for (int jj = 0; jj < 4; ++jj) {
        const int m2 = w * 32 + mt * 16 + lhi * 4 + jj;
        const int e2 = et * 16 + llo;
        atomicAdd(&ctxEG[((size_t)bh * 256 + m2) * 64 + e2], cacc[mt][et][jj]);
      }
}

// ---------------------------------------------------------------------------
// combine: kshat[m] = e^{-stab}*Esum + eps*N; ctxhat -> transposed bf16 pair.
// ---------------------------------------------------------------------------
__global__ __launch_bounds__(256) void perf_combine(
    const unsigned* __restrict__ stabKey, const float* __restrict__ EsumG,
    const float* __restrict__ VsumG, const float* __restrict__ ctxEG,
    float* __restrict__ kshatG, short* __restrict__ ctHG, short* __restrict__ ctLG) {
  const int bh = blockIdx.x, t = threadIdx.x;
  const float esc = __expf(-keyToFloat(stabKey[bh]));
  kshatG[bh * 256 + t] = esc * EsumG[bh * 256 + t] + kEps * 4096.0f;
  for (int e = 0; e < 64; ++e) {
    const float v2 = esc * ctxEG[((size_t)bh * 256 + t) * 64 + e] + kEps * VsumG[bh * 64 + e];
    short hh, ll;
    splitbf(v2, hh, ll);
    ctHG[((size_t)bh * 64 + e) * 256 + t] = hh;
    ctLG[((size_t)bh * 64 + e) * 256 + t] = ll;
  }
}

// ---------------------------------------------------------------------------
// qside: grid (96, 64), block 512. 64 q-rows/block. LDS 65.5K. (unchanged r9)
// ---------------------------------------------------------------------------
__global__ __launch_bounds__(512, 2) void perf_qside(
    const float* __restrict__ Q, const short* __restrict__ PhG,
    const short* __restrict__ PlG, const float* __restrict__ kshatG,
    const short* __restrict__ ctHG, const short* __restrict__ ctLG,
    float* __restrict__ out) {
  const int t = threadIdx.x, bh = blockIdx.x, rb = blockIdx.y;
  const int w = t >> 6, l = t & 63;
  const int rt = w & 3, ms = w >> 2;
  const int lhi = l >> 4, llo = l & 15;
  const int koff = lhi * 8;

  __shared__ short Ph[128][64], Pl[128][64];  // per-phase proj; reused as ctT[64][128]
  __shared__ short qph[64][256];              // q' bf16 (hi only)
  __shared__ float kshatL[256];
  __shared__ unsigned rmaxKey[64];
  __shared__ float denL[64];

  if (t < 64) { rmaxKey[t] = 0u; denL[t] = 0.f; }
  if (t < 256) kshatL[t] = kshatG[bh * 256 + t];

  const int r = rt * 16 + llo;  // this lane's q-row

  // Q fragments + diag (global direct; folded norm)
  short8v qh[2], ql[2];
  float dgq;
  {
    const float* qs = Q + ((size_t)bh * Nn + rb * 64 + r) * 64 + koff;
    float4 a0 = *(const float4*)qs;
    float4 a1 = *(const float4*)(qs + 4);
    float4 b0 = *(const float4*)(qs + 32);
    float4 b1 = *(const float4*)(qs + 36);
    float xs[16] = {a0.x, a0.y, a0.z, a0.w, a1.x, a1.y, a1.z, a1.w,
                    b0.x, b0.y, b0.z, b0.w, b1.x, b1.y, b1.z, b1.w};
    float s = 0.f;
#pragma unroll
    for (int i = 0; i < 16; ++i) s = fmaf(xs[i], xs[i], s);
    s += __shfl_xor(s, 16);
    s += __shfl_xor(s, 32);
    dgq = s * kDiagCoef;
#pragma unroll
    for (int kb = 0; kb < 2; ++kb) {
      short8v h8, l8;
#pragma unroll
      for (int i = 0; i < 8; ++i) {
        short hh, ll;
        splitbf(kNorm * xs[kb * 8 + i], hh, ll);
        h8[i] = hh; l8[i] = ll;
      }
      qh[kb] = h8; ql[kb] = l8;
    }
  }

  // dd GEMM in 2 phases of 128 m (proj half staged per phase)
  f32x4 dacc[8];
#pragma unroll
  for (int ph = 0; ph < 2; ++ph) {
    __syncthreads();  // init / prev-phase dd reads done
    {  // stage proj half ph
      const int i = t >> 2, d0 = (t & 3) * 16;
      const short* gh = PhG + (ph * 128 + i) * 64 + d0;
      const short* gl = PlG + (ph * 128 + i) * 64 + d0;
      const int c0 = sw8(i, d0), c1 = sw8(i, d0 + 8);
      *(short8v*)&Ph[i][c0] = *(const short8v*)gh;
      *(short8v*)&Ph[i][c1] = *(const short8v*)(gh + 8);
      *(short8v*)&Pl[i][c0] = *(const short8v*)gl;
      *(short8v*)&Pl[i][c1] = *(const short8v*)(gl + 8);
    }
    __syncthreads();
#pragma unroll
    for (int mt = 0; mt < 4; ++mt) {
      const int mrow = ms * 64 + mt * 16 + llo;
      f32x4 acc = f32x4{0.f, 0.f, 0.f, 0.f};
#pragma unroll
      for (int kb = 0; kb < 2; ++kb) {
        const int c = sw8(mrow, kb * 32 + koff);
        short8v pbh = *(const short8v*)&Ph[mrow][c];
        short8v pbl = *(const short8v*)&Pl[mrow][c];
        acc = MFMA32(pbh, qh[kb], acc);
        acc = MFMA32(pbh, ql[kb], acc);
        acc = MFMA32(pbl, qh[kb], acc);
      }
      dacc[ph * 4 + mt] = acc;  // dd[m = ph*128+ms*64+mt*16+lhi*4+jj][r]
    }
  }

  // rowmax over this wave's 128 m's, merged across ms pair via LDS
  {
    float mx = dacc[0][0];
#pragma unroll
    for (int i = 0; i < 8; ++i)
#pragma unroll
      for (int jj = 0; jj < 4; ++jj) mx = fmaxf(mx, dacc[i][jj]);
    mx = fmaxf(mx, __shfl_xor(mx, 16));
    mx = fmaxf(mx, __shfl_xor(mx, 32));
    if (l < 16) atomicMax(&rmaxKey[rt * 16 + l], floatKey(mx));
  }
  __syncthreads();

  // exp -> q' (bf16 hi), den from the SAME rounded weights
  {
    const float shift = dgq + keyToFloat(rmaxKey[r]);
    float den = 0.f;
#pragma unroll
    for (int i = 0; i < 8; ++i) {
      const int m0 = (i >> 2) * 128 + ms * 64 + (i & 3) * 16 + lhi * 4;
      const f32x4 ksv = *(const f32x4*)&kshatL[m0];
      short4v h4;
#pragma unroll
      for (int jj = 0; jj < 4; ++jj) {
        float qv = __expf(dacc[i][jj] - shift) + kEps;
        short hh = f2bf(qv);
        h4[jj] = hh;
        den = fmaf(bf2f(hh), ksv[jj], den);  // consistent with numerator
      }
      const int c = m0 ^ ((r & 31) << 3);
      *(short4v*)&qph[r][c] = h4;
    }
    den += __shfl_xor(den, 16);
    den += __shfl_xor(den, 32);
    if (l < 16) atomicAdd(&denL[rt * 16 + l], den);
  }

  // output GEMM: ctT staged per m-half into reused Ph/Pl space; 2-term
  short(*ctTh)[128] = (short(*)[128])Ph;
  short(*ctTl)[128] = (short(*)[128])Pl;
  f32x4 oacc[2] = {f32x4{0.f, 0.f, 0.f, 0.f}, f32x4{0.f, 0.f, 0.f, 0.f}};
#pragma unroll
  for (int mh2 = 0; mh2 < 2; ++mh2) {
    __syncthreads();  // qp/den writes done (mh2=0) / prev MFMAs done (mh2=1)
    {  // stage ctxhatT half
      const int e = t >> 3, mg = t & 7;
      const short* gh = ctHG + ((size_t)bh * 64 + e) * 256 + mh2 * 128 + mg * 16;
      const short* gl = ctLG + ((size_t)bh * 64 + e) * 256 + mh2 * 128 + mg * 16;
      short8v a0 = *(const short8v*)gh;
      short8v a1 = *(const short8v*)(gh + 8);
      short8v b0 = *(const short8v*)gl;
      short8v b1 = *(const short8v*)(gl + 8);
      *(short8v*)&ctTh[e][sw16(e, mg * 16)] = a0;
      *(short8v*)&ctTh[e][sw16(e, mg * 16 + 8)] = a1;
      *(short8v*)&ctTl[e][sw16(e, mg * 16)] = b0;
      *(short8v*)&ctTl[e][sw16(e, mg * 16 + 8)] = b1;
    }
    __syncthreads();
#pragma unroll
    for (int kc = 0; kc < 4; ++kc) {
      const int mb = mh2 * 128 + kc * 32 + koff;
      const int ca = mb ^ ((r & 31) << 3);
      short8v qh8 = *(const short8v*)&qph[r][ca];
#pragma unroll
      for (int et = 0; et < 2; ++et) {
        const int erow = (ms * 2 + et) * 16 + llo;
        const int cb = sw16(erow, kc * 32 + koff);
        short8v th = *(const short8v*)&ctTh[erow][cb];
        short8v tl = *(const short8v*)&ctTl[erow][cb];
        oacc[et] = MFMA32(qh8, th, oacc[et]);
        oacc[et] = MFMA32(qh8, tl, oacc[et]);
      }
    }
  }

  // epilogue
  float inv[4];
#pragma unroll
  for (int jj = 0; jj < 4; ++jj) inv[jj] = 1.0f / denL[rt * 16 + lhi * 4 + jj];
#pragma unroll
  for (int et = 0; et < 2; ++et)
#pragma unroll
    for (int jj = 0; jj < 4; ++jj) {
      const int ro = rt * 16 + lhi * 4 + jj;
      const int e2 = (ms * 2 + et) * 16 + llo;
      out[((size_t)bh * Nn + rb * 64 + ro) * 64 + e2] = oacc[et][jj] * inv[jj];
    }
}

extern "C" void kernel_launch(void* const* d_in, const int* in_sizes, int n_in,
                              void* d_out, int out_size, void* d_ws, size_t ws_size,
                              hipStream_t stream) {
  const float* q = (const float*)d_in[0];
  const float* k = (const float*)d_in[1];
  const float* v = (const float*)d_in[2];
  const float* proj = (const float*)d_in[3];
  float* outp = (float*)d_out;

  char* ws = (char*)d_ws;
  unsigned* stabKey = (unsigned*)(ws + oStab);
  float* EsumG = (float*)(ws + oEsum);
  float* VsumG = (float*)(ws + oVsum);
  float* kshatG = (float*)(ws + oKshat);
  float* ctxEG = (float*)(ws + oCtxE);
  short* ctHG = (short*)(ws + oCtH);
  short* ctLG = (short*)(ws + oCtL);
  short* PhG = (short*)(ws + oPh);
  short* PlG = (short*)(ws + oPl);

  hipMemsetAsync(d_ws, 0, kZeroBytes, stream);
  perf_prep<<<16, 256, 0, stream>>>(proj, PhG, PlG);
  perf_kside<<<dim3(BHn, 16), 512, 0, stream>>>(k, v, PhG, PlG, stabKey, EsumG, VsumG, ctxEG);
  perf_combine<<<BHn, 256, 0, stream>>>(stabKey, EsumG, VsumG, ctxEG, kshatG, ctHG, ctLG);
  perf_qside<<<dim3(BHn, 64), 512, 0, stream>>>(q, PhG, PlG, kshatG, ctHG, ctLG, outp);
}

// Round 11
// 280.130 us; speedup vs baseline: 1.3781x; 1.0478x over previous
//
#include <hip/hip_runtime.h>
#include <hip/hip_bf16.h>
#include <float.h>

// Performer FastAttention (FAVOR+), MFMA bf16-split v6.
// Round 11: T14 async-STAGE split. kside: next-sub K/V global loads issued
// into regs during current-sub compute (HBM latency hidden under MFMA/exp).
// qside: proj-h1 / ctT-h0 / ctT-h1 loads prefetched one phase ahead.

typedef __attribute__((ext_vector_type(8))) short short8v;
typedef __attribute__((ext_vector_type(4))) short short4v;
typedef __attribute__((ext_vector_type(4))) float f32x4;

#define MFMA32(a, b, c) __builtin_amdgcn_mfma_f32_16x16x32_bf16(a, b, c, 0, 0, 0)

#if defined(__has_builtin)
#if __has_builtin(__builtin_amdgcn_mfma_f32_16x16x16bf16_1k)
#define HAVE_MFMA16_1K 1
#endif
#endif
#ifdef HAVE_MFMA16_1K
#define MFMA16K(a, b, c) __builtin_amdgcn_mfma_f32_16x16x16bf16_1k(a, b, c, 0, 0, 0)
#else
static __device__ __forceinline__ f32x4 mfma16k_asm(short4v a, short4v b, f32x4 c) {
  asm("s_nop 1\n\tv_mfma_f32_16x16x16_bf16 %0, %1, %2, %0" : "+v"(c) : "v"(a), "v"(b));
  return c;
}
#define MFMA16K(a, b, c) mfma16k_asm(a, b, c)
#endif

namespace {
constexpr int Nn = 4096, Dd = 64, BHn = 96;
constexpr float kNorm = 0.35355339059327379f;  // 64^-0.25
constexpr float kDiagCoef = 0.0625f;           // 0.5 * 64^-0.5
constexpr float kEps = 1e-4f;

constexpr size_t oStab  = 0;                                   // 96 u32
constexpr size_t oEsum  = 512;                                 // 96*256 f32
constexpr size_t oVsum  = oEsum + (size_t)BHn * 256 * 4;       // 96*64 f32
constexpr size_t oKshat = oVsum + (size_t)BHn * 64 * 4;        // 96*256 f32
constexpr size_t oCtxE  = oKshat + (size_t)BHn * 256 * 4;      // 96*256*64 f32
constexpr size_t oCtH   = oCtxE + (size_t)BHn * 256 * 64 * 4;  // 96*64*256 bf16
constexpr size_t oCtL   = oCtH + (size_t)BHn * 64 * 256 * 2;
constexpr size_t oPh    = oCtL + (size_t)BHn * 64 * 256 * 2;   // 256*64 bf16
constexpr size_t oPl    = oPh + (size_t)256 * 64 * 2;
constexpr size_t kZeroBytes = oCtH;  // zero stab..ctxE accumulators
}

static __device__ __forceinline__ unsigned floatKey(float f) {
  unsigned b = __float_as_uint(f);
  return (b & 0x80000000u) ? ~b : (b | 0x80000000u);
}
static __device__ __forceinline__ float keyToFloat(unsigned k) {
  unsigned b = (k & 0x80000000u) ? (k & 0x7fffffffu) : ~k;
  return __uint_as_float(b);
}
static __device__ __forceinline__ short f2bf(float x) {
  union { __hip_bfloat16 h; short s; } u;
  u.h = __float2bfloat16(x);
  return u.s;
}
static __device__ __forceinline__ float bf2f(short s) {
  return __uint_as_float(((unsigned)(unsigned short)s) << 16);
}
static __device__ __forceinline__ void splitbf(float x, short& h, short& l) {
  h = f2bf(x);
  l = f2bf(x - bf2f(h));
}
static __device__ __forceinline__ int sw8(int row, int col)  { return col ^ ((row & 7) << 3); }
static __device__ __forceinline__ int sw16(int row, int col) { return col ^ ((row & 15) << 3); }

// ---------------------------------------------------------------------------
// prep: split proj into bf16 hi/lo, linear [m][d] layout in ws.
// ---------------------------------------------------------------------------
__global__ void perf_prep(const float* __restrict__ proj, short* __restrict__ Ph,
                          short* __restrict__ Pl) {
  const int i = (blockIdx.x * 256 + threadIdx.x) * 4;  // 16384 elems
  float4 v = *(const float4*)(proj + i);
  float xs[4] = {v.x, v.y, v.z, v.w};
  short4v h, l;
#pragma unroll
  for (int j = 0; j < 4; ++j) {
    short hh, ll;
    splitbf(xs[j], hh, ll);
    h[j] = hh;
    l[j] = ll;
  }
  *(short4v*)(Ph + i) = h;
  *(short4v*)(Pl + i) = l;
}

// ---------------------------------------------------------------------------
// kside: grid (96, 16), block 512 (8 waves). 256 k-rows/block, 4 subs of 64.
// Wave w owns m-strip w*32..+32 (proj frags in regs). dd via 16x16x32 MFMA;
// exp'd accumulator feeds ctx 16x16x16 MFMAs directly from regs.
// T14: next-sub K/V loads issued into regs during current-sub compute.
// ---------------------------------------------------------------------------
__global__ __launch_bounds__(512, 2) void perf_kside(
    const float* __restrict__ K, const float* __restrict__ V,
    const short* __restrict__ PhG, const short* __restrict__ PlG,
    unsigned* __restrict__ stabKey, float* __restrict__ EsumG,
    float* __restrict__ VsumG, float* __restrict__ ctxEG) {
  const int t = threadIdx.x, bh = blockIdx.x, chunk = blockIdx.y;
  const int w = t >> 6, l = t & 63;
  const int lhi = l >> 4, llo = l & 15;
  const int koff = lhi * 8;

  __shared__ short Kh[64][64], Kl[64][64];
  __shared__ short Vh[64][64], Vl[64][64];      // V^T: [e][n]
  __shared__ float diag[64];
  __shared__ float rpartV[8][64];
  __shared__ float wpmax[8];

  // proj fragments in registers (wave's 32-m strip, both kb slices, hi+lo)
  short8v prh[2][2], prl[2][2];
#pragma unroll
  for (int mt = 0; mt < 2; ++mt)
#pragma unroll
    for (int kb = 0; kb < 2; ++kb) {
      const int m = w * 32 + mt * 16 + llo;
      prh[mt][kb] = *(const short8v*)(PhG + m * 64 + kb * 32 + koff);
      prl[mt][kb] = *(const short8v*)(PlG + m * 64 + kb * 32 + koff);
    }

  float mx = -FLT_MAX, vsum_r = 0.f;
  f32x4 cacc[2][4];
  float es[2] = {0.f, 0.f};
#pragma unroll
  for (int a = 0; a < 2; ++a)
#pragma unroll
    for (int b = 0; b < 4; ++b) cacc[a][b] = f32x4{0.f, 0.f, 0.f, 0.f};

  const size_t base = ((size_t)bh * Nn + chunk * 256) * Dd;
  const int nK = t >> 3, d0K = (t & 7) * 8;
  const int eV = l, n0V = w * 8;
  const float* Kbase = K + base + (size_t)nK * 64 + d0K;
  const float* Vbase = V + base + (size_t)n0V * 64 + eV;

  // prologue: sub 0 staging loads -> regs
  float4 ka = *(const float4*)Kbase;
  float4 kb4 = *(const float4*)(Kbase + 4);
  float vv[8];
#pragma unroll
  for (int i = 0; i < 8; ++i) vv[i] = Vbase[i * 64];

  for (int sub = 0; sub < 4; ++sub) {
    __syncthreads();  // prev sub's consumers done with Kh/Vh
    {  // split & write K (+diag partial) from regs
      float xs[8] = {ka.x, ka.y, ka.z, ka.w, kb4.x, kb4.y, kb4.z, kb4.w};
      float s = 0.f;
#pragma unroll
      for (int i = 0; i < 8; ++i) s = fmaf(xs[i], xs[i], s);
      s += __shfl_xor(s, 1); s += __shfl_xor(s, 2); s += __shfl_xor(s, 4);
      if ((t & 7) == 0) diag[nK] = s * kDiagCoef;
      short8v h8, l8;
#pragma unroll
      for (int i = 0; i < 8; ++i) {
        short hh, ll;
        splitbf(kNorm * xs[i], hh, ll);
        h8[i] = hh; l8[i] = ll;
      }
      const int c = sw8(nK, d0K);
      *(short8v*)&Kh[nK][c] = h8;
      *(short8v*)&Kl[nK][c] = l8;
    }
    {  // split & write V^T from regs (+vsum)
      short8v h8, l8;
#pragma unroll
      for (int i = 0; i < 8; ++i) {
        vsum_r += vv[i];
        short hh, ll;
        splitbf(vv[i], hh, ll);
        h8[i] = hh; l8[i] = ll;
      }
      const int c = sw8(eV, n0V);
      *(short8v*)&Vh[eV][c] = h8;
      *(short8v*)&Vl[eV][c] = l8;
    }
    if (sub < 3) {  // T14: issue next-sub loads; complete under compute below
      const float* kn = Kbase + (size_t)(sub + 1) * 64 * 64;
      const float* vn = Vbase + (size_t)(sub + 1) * 64 * 64;
      ka = *(const float4*)kn;
      kb4 = *(const float4*)(kn + 4);
#pragma unroll
      for (int i = 0; i < 8; ++i) vv[i] = vn[i * 64];
    }
    __syncthreads();  // tiles ready

#pragma unroll
    for (int b = 0; b < 4; ++b) {
      const int arow = b * 16 + llo;
      short8v kh[2], kl[2];
#pragma unroll
      for (int kb = 0; kb < 2; ++kb) {
        const int c = sw8(arow, kb * 32 + koff);
        kh[kb] = *(const short8v*)&Kh[arow][c];
        kl[kb] = *(const short8v*)&Kl[arow][c];
      }
      short4v vh[4], vl[4];
#pragma unroll
      for (int et = 0; et < 4; ++et) {
        const int ecol = et * 16 + llo;
        const int cc = sw8(ecol, b * 16 + lhi * 4);
        vh[et] = *(const short4v*)&Vh[ecol][cc];
        vl[et] = *(const short4v*)&Vl[ecol][cc];
      }
      const f32x4 dg = *(const f32x4*)&diag[b * 16 + lhi * 4];

#pragma unroll
      for (int mt = 0; mt < 2; ++mt) {
        f32x4 acc = f32x4{0.f, 0.f, 0.f, 0.f};
#pragma unroll
        for (int kb = 0; kb < 2; ++kb) {
          acc = MFMA32(kh[kb], prh[mt][kb], acc);
          acc = MFMA32(kh[kb], prl[mt][kb], acc);
          acc = MFMA32(kl[kb], prh[mt][kb], acc);
        }
        short4v h4, l4;
        float esa = 0.f;
#pragma unroll
        for (int jj = 0; jj < 4; ++jj) {
          float dd = acc[jj];
          mx = fmaxf(mx, dd);
          float E = __expf(dd - dg[jj]);
          esa += E;
          short hh, ll;
          splitbf(E, hh, ll);
          h4[jj] = hh; l4[jj] = ll;
        }
        es[mt] += esa;
#pragma unroll
        for (int et = 0; et < 4; ++et) {
          f32x4 a2 = cacc[mt][et];
          a2 = MFMA16K(h4, vh[et], a2);
          a2 = MFMA16K(h4, vl[et], a2);
          a2 = MFMA16K(l4, vh[et], a2);
          cacc[mt][et] = a2;
        }
      }
    }
  }

  // reductions
#pragma unroll
  for (int off = 32; off; off >>= 1) mx = fmaxf(mx, __shfl_xor(mx, off));
  if (l == 0) wpmax[w] = mx;
#pragma unroll
  for (int mt = 0; mt < 2; ++mt) {
    float v2 = es[mt];
    v2 += __shfl_xor(v2, 16);
    v2 += __shfl_xor(v2, 32);
    if (l < 16) atomicAdd(&EsumG[bh * 256 + w * 32 + mt * 16 + l], v2);
  }
  rpartV[w][l] = vsum_r;
  __syncthreads();
  if (t < 64) {
    float s2 = 0.f;
#pragma unroll
    for (int w2 = 0; w2 < 8; ++w2) s2 += rpartV[w2][t];
    atomicAdd(&VsumG[bh * 64 + t], s2);
  }
  if (t == 0) {
    float b = wpmax[0];
#pragma unroll
    for (int w2 = 1; w2 < 8; ++w2) b = fmaxf(b, wpmax[w2]);
    atomicMax(stabKey + bh, floatKey(b));
  }
#pragma unroll
  for (int mt = 0; mt < 2; ++mt)
#pragma unroll
    for (int et = 0; et < 4; ++et)
#pragma unroll
      for (int jj = 0; jj < 4; ++jj) {
        const int m2 = w * 32 + mt * 16 + lhi * 4 + jj;
        const int e2 = et * 16 + llo;
        atomicAdd(&ctxEG[((size_t)bh * 256 + m2) * 64 + e2], cacc[mt][et][jj]);
      }
}

// ---------------------------------------------------------------------------
// combine: kshat[m] = e^{-stab}*Esum + eps*N; ctxhat -> transposed bf16 pair.
// ---------------------------------------------------------------------------
__global__ __launch_bounds__(256) void perf_combine(
    const unsigned* __restrict__ stabKey, const float* __restrict__ EsumG,
    const float* __restrict__ VsumG, const float* __restrict__ ctxEG,
    float* __restrict__ kshatG, short* __restrict__ ctHG, short* __restrict__ ctLG) {
  const int bh = blockIdx.x, t = threadIdx.x;
  const float esc = __expf(-keyToFloat(stabKey[bh]));
  kshatG[bh * 256 + t] = esc * EsumG[bh * 256 + t] + kEps * 4096.0f;
  for (int e = 0; e < 64; ++e) {
    const float v2 = esc * ctxEG[((size_t)bh * 256 + t) * 64 + e] + kEps * VsumG[bh * 64 + e];
    short hh, ll;
    splitbf(v2, hh, ll);
    ctHG[((size_t)bh * 64 + e) * 256 + t] = hh;
    ctLG[((size_t)bh * 64 + e) * 256 + t] = ll;
  }
}

// ---------------------------------------------------------------------------
// qside: grid (96, 64), block 512. 64 q-rows/block. LDS 65.5K.
// T14: proj-h1 / ctT-h0 / ctT-h1 global loads prefetched one phase ahead.
// ---------------------------------------------------------------------------
__global__ __launch_bounds__(512, 2) void perf_qside(
    const float* __restrict__ Q, const short* __restrict__ PhG,
    const short* __restrict__ PlG, const float* __restrict__ kshatG,
    const short* __restrict__ ctHG, const short* __restrict__ ctLG,
    float* __restrict__ out) {
  const int t = threadIdx.x, bh = blockIdx.x, rb = blockIdx.y;
  const int w = t >> 6, l = t & 63;
  const int rt = w & 3, ms = w >> 2;
  const int lhi = l >> 4, llo = l & 15;
  const int koff = lhi * 8;

  __shared__ short Ph[128][64], Pl[128][64];  // per-phase proj; reused as ctT[64][128]
  __shared__ short qph[64][256];              // q' bf16 (hi only)
  __shared__ float kshatL[256];
  __shared__ unsigned rmaxKey[64];
  __shared__ float denL[64];

  // staging coords
  const int iP = t >> 2, d0P = (t & 3) * 16;          // proj staging
  const int eC = t >> 3, mgC = t & 7;                 // ctT staging

  // issue proj h0 loads immediately
  short8v p0a = *(const short8v*)(PhG + iP * 64 + d0P);
  short8v p0b = *(const short8v*)(PhG + iP * 64 + d0P + 8);
  short8v p0c = *(const short8v*)(PlG + iP * 64 + d0P);
  short8v p0d = *(const short8v*)(PlG + iP * 64 + d0P + 8);

  if (t < 64) { rmaxKey[t] = 0u; denL[t] = 0.f; }
  if (t < 256) kshatL[t] = kshatG[bh * 256 + t];

  const int r = rt * 16 + llo;  // this lane's q-row

  // Q fragments + diag (global direct; folded norm) — overlaps proj loads
  short8v qh[2], ql[2];
  float dgq;
  {
    const float* qs = Q + ((size_t)bh * Nn + rb * 64 + r) * 64 + koff;
    float4 a0 = *(const float4*)qs;
    float4 a1 = *(const float4*)(qs + 4);
    float4 b0 = *(const float4*)(qs + 32);
    float4 b1 = *(const float4*)(qs + 36);
    float xs[16] = {a0.x, a0.y, a0.z, a0.w, a1.x, a1.y, a1.z, a1.w,
                    b0.x, b0.y, b0.z, b0.w, b1.x, b1.y, b1.z, b1.w};
    float s = 0.f;
#pragma unroll
    for (int i = 0; i < 16; ++i) s = fmaf(xs[i], xs[i], s);
    s += __shfl_xor(s, 16);
    s += __shfl_xor(s, 32);
    dgq = s * kDiagCoef;
#pragma unroll
    for (int kb = 0; kb < 2; ++kb) {
      short8v h8, l8;
#pragma unroll
      for (int i = 0; i < 8; ++i) {
        short hh, ll;
        splitbf(kNorm * xs[kb * 8 + i], hh, ll);
        h8[i] = hh; l8[i] = ll;
      }
      qh[kb] = h8; ql[kb] = l8;
    }
  }
  __syncthreads();  // init visible

  // write proj h0; issue proj h1 loads
  {
    const int c0 = sw8(iP, d0P), c1 = sw8(iP, d0P + 8);
    *(short8v*)&Ph[iP][c0] = p0a;
    *(short8v*)&Ph[iP][c1] = p0b;
    *(short8v*)&Pl[iP][c0] = p0c;
    *(short8v*)&Pl[iP][c1] = p0d;
  }
  p0a = *(const short8v*)(PhG + (128 + iP) * 64 + d0P);
  p0b = *(const short8v*)(PhG + (128 + iP) * 64 + d0P + 8);
  p0c = *(const short8v*)(PlG + (128 + iP) * 64 + d0P);
  p0d = *(const short8v*)(PlG + (128 + iP) * 64 + d0P + 8);
  __syncthreads();

  f32x4 dacc[8];
#pragma unroll
  for (int mt = 0; mt < 4; ++mt) {  // dd ph0 (proj h1 loads in flight)
    const int mrow = ms * 64 + mt * 16 + llo;
    f32x4 acc = f32x4{0.f, 0.f, 0.f, 0.f};
#pragma unroll
    for (int kb = 0; kb < 2; ++kb) {
      const int c = sw8(mrow, kb * 32 + koff);
      short8v pbh = *(const short8v*)&Ph[mrow][c];
      short8v pbl = *(const short8v*)&Pl[mrow][c];
      acc = MFMA32(pbh, qh[kb], acc);
      acc = MFMA32(pbh, ql[kb], acc);
      acc = MFMA32(pbl, qh[kb], acc);
    }
    dacc[mt] = acc;
  }
  __syncthreads();  // ph0 dd reads done

  // write proj h1; issue ctT h0 loads
  {
    const int c0 = sw8(iP, d0P), c1 = sw8(iP, d0P + 8);
    *(short8v*)&Ph[iP][c0] = p0a;
    *(short8v*)&Ph[iP][c1] = p0b;
    *(short8v*)&Pl[iP][c0] = p0c;
    *(short8v*)&Pl[iP][c1] = p0d;
  }
  {
    const short* gh = ctHG + ((size_t)bh * 64 + eC) * 256 + mgC * 16;
    const short* gl = ctLG + ((size_t)bh * 64 + eC) * 256 + mgC * 16;
    p0a = *(const short8v*)gh;
    p0b = *(const short8v*)(gh + 8);
    p0c = *(const short8v*)gl;
    p0d = *(const short8v*)(gl + 8);
  }
  __syncthreads();

#pragma unroll
  for (int mt = 0; mt < 4; ++mt) {  // dd ph1 (ctT h0 loads in flight)
    const int mrow = ms * 64 + mt * 16 + llo;
    f32x4 acc = f32x4{0.f, 0.f, 0.f, 0.f};
#pragma unroll
    for (int kb = 0; kb < 2; ++kb) {
      const int c = sw8(mrow, kb * 32 + koff);
      short8v pbh = *(const short8v*)&Ph[mrow][c];
      short8v pbl = *(const short8v*)&Pl[mrow][c];
      acc = MFMA32(pbh, qh[kb], acc);
      acc = MFMA32(pbh, ql[kb], acc);
      acc = MFMA32(pbl, qh[kb], acc);
    }
    dacc[4 + mt] = acc;  // dd[m = 128+ms*64+mt*16+lhi*4+jj][r]
  }

  // rowmax over this wave's 128 m's, merged across ms pair via LDS
  {
    float mx = dacc[0][0];
#pragma unroll
    for (int i = 0; i < 8; ++i)
#pragma unroll
      for (int jj = 0; jj < 4; ++jj) mx = fmaxf(mx, dacc[i][jj]);
    mx = fmaxf(mx, __shfl_xor(mx, 16));
    mx = fmaxf(mx, __shfl_xor(mx, 32));
    if (l < 16) atomicMax(&rmaxKey[rt * 16 + l], floatKey(mx));
  }
  __syncthreads();

  // exp -> q' (bf16 hi), den from the SAME rounded weights
  {
    const float shift = dgq + keyToFloat(rmaxKey[r]);
    float den = 0.f;
#pragma unroll
    for (int i = 0; i < 8; ++i) {
      const int m0 = (i >> 2) * 128 + ms * 64 + (i & 3) * 16 + lhi * 4;
      const f32x4 ksv = *(const f32x4*)&kshatL[m0];
      short4v h4;
#pragma unroll
      for (int jj = 0; jj < 4; ++jj) {
        float qv = __expf(dacc[i][jj] - shift) + kEps;
        short hh = f2bf(qv);
        h4[jj] = hh;
        den = fmaf(bf2f(hh), ksv[jj], den);  // consistent with numerator
      }
      const int c = m0 ^ ((r & 31) << 3);
      *(short4v*)&qph[r][c] = h4;
    }
    den += __shfl_xor(den, 16);
    den += __shfl_xor(den, 32);
    if (l < 16) atomicAdd(&denL[rt * 16 + l], den);
  }
  __syncthreads();  // qph/den visible; Ph/Pl dd reads done

  short(*ctTh)[128] = (short(*)[128])Ph;
  short(*ctTl)[128] = (short(*)[128])Pl;
  f32x4 oacc[2] = {f32x4{0.f, 0.f, 0.f, 0.f}, f32x4{0.f, 0.f, 0.f, 0.f}};

  // write ctT h0; issue ctT h1 loads
  {
    *(short8v*)&ctTh[eC][sw16(eC, mgC * 16)] = p0a;
    *(short8v*)&ctTh[eC][sw16(eC, mgC * 16 + 8)] = p0b;
    *(short8v*)&ctTl[eC][sw16(eC, mgC * 16)] = p0c;
    *(short8v*)&ctTl[eC][sw16(eC, mgC * 16 + 8)] = p0d;
  }
  {
    const short* gh = ctHG + ((size_t)bh * 64 + eC) * 256 + 128 + mgC * 16;
    const short* gl = ctLG + ((size_t)bh * 64 + eC) * 256 + 128 + mgC * 16;
    p0a = *(const short8v*)gh;
    p0b = *(const short8v*)(gh + 8);
    p0c = *(const short8v*)gl;
    p0d = *(const short8v*)(gl + 8);
  }
  __syncthreads();

#pragma unroll
  for (int mh2 = 0; mh2 < 2; ++mh2) {
    if (mh2 == 1) {
      __syncthreads();  // out GEMM h0 reads done
      *(short8v*)&ctTh[eC][sw16(eC, mgC * 16)] = p0a;
      *(short8v*)&ctTh[eC][sw16(eC, mgC * 16 + 8)] = p0b;
      *(short8v*)&ctTl[eC][sw16(eC, mgC * 16)] = p0c;
      *(short8v*)&ctTl[eC][sw16(eC, mgC * 16 + 8)] = p0d;
      __syncthreads();
    }
#pragma unroll
    for (int kc = 0; kc < 4; ++kc) {
      const int mb = mh2 * 128 + kc * 32 + koff;
      const int ca = mb ^ ((r & 31) << 3);
      short8v qh8 = *(const short8v*)&qph[r][ca];
#pragma unroll
      for (int et = 0; et < 2; ++et) {
        const int erow = (ms * 2 + et) * 16 + llo;
        const int cb = sw16(erow, kc * 32 + koff);
        short8v th = *(const short8v*)&ctTh[erow][cb];
        short8v tl = *(const short8v*)&ctTl[erow][cb];
        oacc[et] = MFMA32(qh8, th, oacc[et]);
        oacc[et] = MFMA32(qh8, tl, oacc[et]);
      }
    }
  }

  // epilogue
  float inv[4];
#pragma unroll
  for (int jj = 0; jj < 4; ++jj) inv[jj] = 1.0f / denL[rt * 16 + lhi * 4 + jj];
#pragma unroll
  for (int et = 0; et < 2; ++et)
#pragma unroll
    for (int jj = 0; jj < 4; ++jj) {
      const int ro = rt * 16 + lhi * 4 + jj;
      const int e2 = (ms * 2 + et) * 16 + llo;
      out[((size_t)bh * Nn + rb * 64 + ro) * 64 + e2] = oacc[et][jj] * inv[jj];
    }
}

extern "C" void kernel_launch(void* const* d_in, const int* in_sizes, int n_in,
                              void* d_out, int out_size, void* d_ws, size_t ws_size,
                              hipStream_t stream) {
  const float* q = (const float*)d_in[0];
  const float* k = (const float*)d_in[1];
  const float* v = (const float*)d_in[2];
  const float* proj = (const float*)d_in[3];
  float* outp = (float*)d_out;

  char* ws = (char*)d_ws;
  unsigned* stabKey = (unsigned*)(ws + oStab);
  float* EsumG = (float*)(ws + oEsum);
  float* VsumG = (float*)(ws + oVsum);
  float* kshatG = (float*)(ws + oKshat);
  float* ctxEG = (float*)(ws + oCtxE);
  short* ctHG = (short*)(ws + oCtH);
  short* ctLG = (short*)(ws + oCtL);
  short* PhG = (short*)(ws + oPh);
  short* PlG = (short*)(ws + oPl);

  hipMemsetAsync(d_ws, 0, kZeroBytes, stream);
  perf_prep<<<16, 256, 0, stream>>>(proj, PhG, PlG);
  perf_kside<<<dim3(BHn, 16), 512, 0, stream>>>(k, v, PhG, PlG, stabKey, EsumG, VsumG, ctxEG);
  perf_combine<<<BHn, 256, 0, stream>>>(stabKey, EsumG, VsumG, ctxEG, kshatG, ctHG, ctLG);
  perf_qside<<<dim3(BHn, 64), 512, 0, stream>>>(q, PhG, PlG, kshatG, ctHG, ctLG, outp);
}

// Round 12
// 269.557 us; speedup vs baseline: 1.4321x; 1.0392x over previous
//
#include <hip/hip_runtime.h>
#include <hip/hip_bf16.h>
#include <float.h>

// Performer FastAttention (FAVOR+), MFMA bf16-split v7.
// Round 12 (kside only): LDS double-buffer + single barrier per sub
// (write tile s+1 before computing tile s -> split/ds_write overlap MFMA);
// ctx GEMM 2-term (drop E_l·V_h residual; Esum uses same rounded E_h so
// the E-rounding cancels in num/den). qside unchanged from r11.

typedef __attribute__((ext_vector_type(8))) short short8v;
typedef __attribute__((ext_vector_type(4))) short short4v;
typedef __attribute__((ext_vector_type(4))) float f32x4;

#define MFMA32(a, b, c) __builtin_amdgcn_mfma_f32_16x16x32_bf16(a, b, c, 0, 0, 0)

#if defined(__has_builtin)
#if __has_builtin(__builtin_amdgcn_mfma_f32_16x16x16bf16_1k)
#define HAVE_MFMA16_1K 1
#endif
#endif
#ifdef HAVE_MFMA16_1K
#define MFMA16K(a, b, c) __builtin_amdgcn_mfma_f32_16x16x16bf16_1k(a, b, c, 0, 0, 0)
#else
static __device__ __forceinline__ f32x4 mfma16k_asm(short4v a, short4v b, f32x4 c) {
  asm("s_nop 1\n\tv_mfma_f32_16x16x16_bf16 %0, %1, %2, %0" : "+v"(c) : "v"(a), "v"(b));
  return c;
}
#define MFMA16K(a, b, c) mfma16k_asm(a, b, c)
#endif

namespace {
constexpr int Nn = 4096, Dd = 64, BHn = 96;
constexpr float kNorm = 0.35355339059327379f;  // 64^-0.25
constexpr float kDiagCoef = 0.0625f;           // 0.5 * 64^-0.5
constexpr float kEps = 1e-4f;

constexpr size_t oStab  = 0;                                   // 96 u32
constexpr size_t oEsum  = 512;                                 // 96*256 f32
constexpr size_t oVsum  = oEsum + (size_t)BHn * 256 * 4;       // 96*64 f32
constexpr size_t oKshat = oVsum + (size_t)BHn * 64 * 4;        // 96*256 f32
constexpr size_t oCtxE  = oKshat + (size_t)BHn * 256 * 4;      // 96*256*64 f32
constexpr size_t oCtH   = oCtxE + (size_t)BHn * 256 * 64 * 4;  // 96*64*256 bf16
constexpr size_t oCtL   = oCtH + (size_t)BHn * 64 * 256 * 2;
constexpr size_t oPh    = oCtL + (size_t)BHn * 64 * 256 * 2;   // 256*64 bf16
constexpr size_t oPl    = oPh + (size_t)256 * 64 * 2;
constexpr size_t kZeroBytes = oCtH;  // zero stab..ctxE accumulators
}

static __device__ __forceinline__ unsigned floatKey(float f) {
  unsigned b = __float_as_uint(f);
  return (b & 0x80000000u) ? ~b : (b | 0x80000000u);
}
static __device__ __forceinline__ float keyToFloat(unsigned k) {
  unsigned b = (k & 0x80000000u) ? (k & 0x7fffffffu) : ~k;
  return __uint_as_float(b);
}
static __device__ __forceinline__ short f2bf(float x) {
  union { __hip_bfloat16 h; short s; } u;
  u.h = __float2bfloat16(x);
  return u.s;
}
static __device__ __forceinline__ float bf2f(short s) {
  return __uint_as_float(((unsigned)(unsigned short)s) << 16);
}
static __device__ __forceinline__ void splitbf(float x, short& h, short& l) {
  h = f2bf(x);
  l = f2bf(x - bf2f(h));
}
static __device__ __forceinline__ int sw8(int row, int col)  { return col ^ ((row & 7) << 3); }
static __device__ __forceinline__ int sw16(int row, int col) { return col ^ ((row & 15) << 3); }

// ---------------------------------------------------------------------------
// prep: split proj into bf16 hi/lo, linear [m][d] layout in ws.
// ---------------------------------------------------------------------------
__global__ void perf_prep(const float* __restrict__ proj, short* __restrict__ Ph,
                          short* __restrict__ Pl) {
  const int i = (blockIdx.x * 256 + threadIdx.x) * 4;  // 16384 elems
  float4 v = *(const float4*)(proj + i);
  float xs[4] = {v.x, v.y, v.z, v.w};
  short4v h, l;
#pragma unroll
  for (int j = 0; j < 4; ++j) {
    short hh, ll;
    splitbf(xs[j], hh, ll);
    h[j] = hh;
    l[j] = ll;
  }
  *(short4v*)(Ph + i) = h;
  *(short4v*)(Pl + i) = l;
}

// ---------------------------------------------------------------------------
// kside: grid (96, 16), block 512 (8 waves). 256 k-rows/block, 4 subs of 64.
// Wave w owns m-strip w*32..+32 (proj frags in regs). dd via 16x16x32 MFMA;
// exp'd accumulator feeds ctx 16x16x16 MFMAs (2-term) directly from regs.
// Double-buffered K/V tiles: write tile s+1 before compute of tile s;
// ONE barrier per sub.
// ---------------------------------------------------------------------------
__global__ __launch_bounds__(512, 2) void perf_kside(
    const float* __restrict__ K, const float* __restrict__ V,
    const short* __restrict__ PhG, const short* __restrict__ PlG,
    unsigned* __restrict__ stabKey, float* __restrict__ EsumG,
    float* __restrict__ VsumG, float* __restrict__ ctxEG) {
  const int t = threadIdx.x, bh = blockIdx.x, chunk = blockIdx.y;
  const int w = t >> 6, l = t & 63;
  const int lhi = l >> 4, llo = l & 15;
  const int koff = lhi * 8;

  __shared__ short Kh[2][64][64], Kl[2][64][64];
  __shared__ short Vh[2][64][64], Vl[2][64][64];   // V^T: [e][n]
  __shared__ float diag[2][64];
  __shared__ float rpartV[8][64];
  __shared__ float wpmax[8];

  // proj fragments in registers (wave's 32-m strip, both kb slices, hi+lo)
  short8v prh[2][2], prl[2][2];
#pragma unroll
  for (int mt = 0; mt < 2; ++mt)
#pragma unroll
    for (int kb = 0; kb < 2; ++kb) {
      const int m = w * 32 + mt * 16 + llo;
      prh[mt][kb] = *(const short8v*)(PhG + m * 64 + kb * 32 + koff);
      prl[mt][kb] = *(const short8v*)(PlG + m * 64 + kb * 32 + koff);
    }

  float mx = -FLT_MAX, vsum_r = 0.f;
  f32x4 cacc[2][4];
  float es[2] = {0.f, 0.f};
#pragma unroll
  for (int a = 0; a < 2; ++a)
#pragma unroll
    for (int b = 0; b < 4; ++b) cacc[a][b] = f32x4{0.f, 0.f, 0.f, 0.f};

  const size_t base = ((size_t)bh * Nn + chunk * 256) * Dd;
  const int nK = t >> 3, d0K = (t & 7) * 8;
  const int eV = l, n0V = w * 8;
  const float* Kp = K + base + (size_t)nK * 64 + d0K;
  const float* Vp = V + base + (size_t)n0V * 64 + eV;

  float4 ka, kb4;
  float vv[8];

  auto LOADR = [&](int s) {
    const float* kn = Kp + (size_t)s * 64 * 64;
    const float* vn = Vp + (size_t)s * 64 * 64;
    ka = *(const float4*)kn;
    kb4 = *(const float4*)(kn + 4);
#pragma unroll
    for (int i = 0; i < 8; ++i) vv[i] = vn[i * 64];
  };
  auto WRITE = [&](int bi) {
    {  // K split + diag partial
      float xs[8] = {ka.x, ka.y, ka.z, ka.w, kb4.x, kb4.y, kb4.z, kb4.w};
      float s = 0.f;
#pragma unroll
      for (int i = 0; i < 8; ++i) s = fmaf(xs[i], xs[i], s);
      s += __shfl_xor(s, 1); s += __shfl_xor(s, 2); s += __shfl_xor(s, 4);
      if ((t & 7) == 0) diag[bi][nK] = s * kDiagCoef;
      short8v h8, l8;
#pragma unroll
      for (int i = 0; i < 8; ++i) {
        short hh, ll;
        splitbf(kNorm * xs[i], hh, ll);
        h8[i] = hh; l8[i] = ll;
      }
      const int c = sw8(nK, d0K);
      *(short8v*)&Kh[bi][nK][c] = h8;
      *(short8v*)&Kl[bi][nK][c] = l8;
    }
    {  // V^T split (+vsum)
      short8v h8, l8;
#pragma unroll
      for (int i = 0; i < 8; ++i) {
        vsum_r += vv[i];
        short hh, ll;
        splitbf(vv[i], hh, ll);
        h8[i] = hh; l8[i] = ll;
      }
      const int c = sw8(eV, n0V);
      *(short8v*)&Vh[bi][eV][c] = h8;
      *(short8v*)&Vl[bi][eV][c] = l8;
    }
  };

  // prologue: tile0 -> buf0; tile1 loads in flight
  LOADR(0);
  WRITE(0);
  LOADR(1);
  __syncthreads();

  for (int s = 0; s < 4; ++s) {
    const int cur = s & 1;
    if (s < 3) {
      WRITE(cur ^ 1);          // tile s+1 -> other buffer (overlaps compute)
      if (s < 2) LOADR(s + 2); // tile s+2 global loads in flight
    }
    // compute on buf cur
#pragma unroll
    for (int b = 0; b < 4; ++b) {
      const int arow = b * 16 + llo;
      short8v kh[2], kl[2];
#pragma unroll
      for (int kb = 0; kb < 2; ++kb) {
        const int c = sw8(arow, kb * 32 + koff);
        kh[kb] = *(const short8v*)&Kh[cur][arow][c];
        kl[kb] = *(const short8v*)&Kl[cur][arow][c];
      }
      short4v vh[4], vl[4];
#pragma unroll
      for (int et = 0; et < 4; ++et) {
        const int ecol = et * 16 + llo;
        const int cc = sw8(ecol, b * 16 + lhi * 4);
        vh[et] = *(const short4v*)&Vh[cur][ecol][cc];
        vl[et] = *(const short4v*)&Vl[cur][ecol][cc];
      }
      const f32x4 dg = *(const f32x4*)&diag[cur][b * 16 + lhi * 4];

#pragma unroll
      for (int mt = 0; mt < 2; ++mt) {
        f32x4 acc = f32x4{0.f, 0.f, 0.f, 0.f};
#pragma unroll
        for (int kb = 0; kb < 2; ++kb) {
          acc = MFMA32(kh[kb], prh[mt][kb], acc);
          acc = MFMA32(kh[kb], prl[mt][kb], acc);
          acc = MFMA32(kl[kb], prh[mt][kb], acc);
        }
        short4v h4;
        float esa = 0.f;
#pragma unroll
        for (int jj = 0; jj < 4; ++jj) {
          float dd = acc[jj];
          mx = fmaxf(mx, dd);
          float E = __expf(dd - dg[jj]);
          short hh = f2bf(E);
          h4[jj] = hh;
          esa += bf2f(hh);  // Esum from the SAME rounded E (num/den cancel)
        }
        es[mt] += esa;
        // ctx GEMM 2-term: E_h·V_h + E_h·V_l
#pragma unroll
        for (int et = 0; et < 4; ++et) {
          f32x4 a2 = cacc[mt][et];
          a2 = MFMA16K(h4, vh[et], a2);
          a2 = MFMA16K(h4, vl[et], a2);
          cacc[mt][et] = a2;
        }
      }
    }
    __syncthreads();
  }

  // reductions
#pragma unroll
  for (int off = 32; off; off >>= 1) mx = fmaxf(mx, __shfl_xor(mx, off));
  if (l == 0) wpmax[w] = mx;
#pragma unroll
  for (int mt = 0; mt < 2; ++mt) {
    float v2 = es[mt];
    v2 += __shfl_xor(v2, 16);
    v2 += __shfl_xor(v2, 32);
    if (l < 16) atomicAdd(&EsumG[bh * 256 + w * 32 + mt * 16 + l], v2);
  }
  rpartV[w][l] = vsum_r;
  __syncthreads();
  if (t < 64) {
    float s2 = 0.f;
#pragma unroll
    for (int w2 = 0; w2 < 8; ++w2) s2 += rpartV[w2][t];
    atomicAdd(&VsumG[bh * 64 + t], s2);
  }
  if (t == 0) {
    float b = wpmax[0];
#pragma unroll
    for (int w2 = 1; w2 < 8; ++w2) b = fmaxf(b, wpmax[w2]);
    atomicMax(stabKey + bh, floatKey(b));
  }
#pragma unroll
  for (int mt = 0; mt < 2; ++mt)
#pragma unroll
    for (int et = 0; et < 4; ++et)
#pragma unroll
      for (int jj = 0; jj < 4; ++jj) {
        const int m2 = w * 32 + mt * 16 + lhi * 4 + jj;
        const int e2 = et * 16 + llo;
        atomicAdd(&ctxEG[((size_t)bh * 256 + m2) * 64 + e2], cacc[mt][et][jj]);
      }
}

// ---------------------------------------------------------------------------
// combine: kshat[m] = e^{-stab}*Esum + eps*N; ctxhat -> transposed bf16 pair.
// ---------------------------------------------------------------------------
__global__ __launch_bounds__(256) void perf_combine(
    const unsigned* __restrict__ stabKey, const float* __restrict__ EsumG,
    const float* __restrict__ VsumG, const float* __restrict__ ctxEG,
    float* __restrict__ kshatG, short* __restrict__ ctHG, short* __restrict__ ctLG) {
  const int bh = blockIdx.x, t = threadIdx.x;
  const float esc = __expf(-keyToFloat(stabKey[bh]));
  kshatG[bh * 256 + t] = esc * EsumG[bh * 256 + t] + kEps * 4096.0f;
  for (int e = 0; e < 64; ++e) {
    const float v2 = esc * ctxEG[((size_t)bh * 256 + t) * 64 + e] + kEps * VsumG[bh * 64 + e];
    short hh, ll;
    splitbf(v2, hh, ll);
    ctHG[((size_t)bh * 64 + e) * 256 + t] = hh;
    ctLG[((size_t)bh * 64 + e) * 256 + t] = ll;
  }
}

// ---------------------------------------------------------------------------
// qside: grid (96, 64), block 512. 64 q-rows/block. LDS 65.5K. (unchanged r11)
// ---------------------------------------------------------------------------
__global__ __launch_bounds__(512, 2) void perf_qside(
    const float* __restrict__ Q, const short* __restrict__ PhG,
    const short* __restrict__ PlG, const float* __restrict__ kshatG,
    const short* __restrict__ ctHG, const short* __restrict__ ctLG,
    float* __restrict__ out) {
  const int t = threadIdx.x, bh = blockIdx.x, rb = blockIdx.y;
  const int w = t >> 6, l = t & 63;
  const int rt = w & 3, ms = w >> 2;
  const int lhi = l >> 4, llo = l & 15;
  const int koff = lhi * 8;

  __shared__ short Ph[128][64], Pl[128][64];  // per-phase proj; reused as ctT[64][128]
  __shared__ short qph[64][256];              // q' bf16 (hi only)
  __shared__ float kshatL[256];
  __shared__ unsigned rmaxKey[64];
  __shared__ float denL[64];

  // staging coords
  const int iP = t >> 2, d0P = (t & 3) * 16;          // proj staging
  const int eC = t >> 3, mgC = t & 7;                 // ctT staging

  // issue proj h0 loads immediately
  short8v p0a = *(const short8v*)(PhG + iP * 64 + d0P);
  short8v p0b = *(const short8v*)(PhG + iP * 64 + d0P + 8);
  short8v p0c = *(const short8v*)(PlG + iP * 64 + d0P);
  short8v p0d = *(const short8v*)(PlG + iP * 64 + d0P + 8);

  if (t < 64) { rmaxKey[t] = 0u; denL[t] = 0.f; }
  if (t < 256) kshatL[t] = kshatG[bh * 256 + t];

  const int r = rt * 16 + llo;  // this lane's q-row

  // Q fragments + diag (global direct; folded norm) — overlaps proj loads
  short8v qh[2], ql[2];
  float dgq;
  {
    const float* qs = Q + ((size_t)bh * Nn + rb * 64 + r) * 64 + koff;
    float4 a0 = *(const float4*)qs;
    float4 a1 = *(const float4*)(qs + 4);
    float4 b0 = *(const float4*)(qs + 32);
    float4 b1 = *(const float4*)(qs + 36);
    float xs[16] = {a0.x, a0.y, a0.z, a0.w, a1.x, a1.y, a1.z, a1.w,
                    b0.x, b0.y, b0.z, b0.w, b1.x, b1.y, b1.z, b1.w};
    float s = 0.f;
#pragma unroll
    for (int i = 0; i < 16; ++i) s = fmaf(xs[i], xs[i], s);
    s += __shfl_xor(s, 16);
    s += __shfl_xor(s, 32);
    dgq = s * kDiagCoef;
#pragma unroll
    for (int kb = 0; kb < 2; ++kb) {
      short8v h8, l8;
#pragma unroll
      for (int i = 0; i < 8; ++i) {
        short hh, ll;
        splitbf(kNorm * xs[kb * 8 + i], hh, ll);
        h8[i] = hh; l8[i] = ll;
      }
      qh[kb] = h8; ql[kb] = l8;
    }
  }
  __syncthreads();  // init visible

  // write proj h0; issue proj h1 loads
  {
    const int c0 = sw8(iP, d0P), c1 = sw8(iP, d0P + 8);
    *(short8v*)&Ph[iP][c0] = p0a;
    *(short8v*)&Ph[iP][c1] = p0b;
    *(short8v*)&Pl[iP][c0] = p0c;
    *(short8v*)&Pl[iP][c1] = p0d;
  }
  p0a = *(const short8v*)(PhG + (128 + iP) * 64 + d0P);
  p0b = *(const short8v*)(PhG + (128 + iP) * 64 + d0P + 8);
  p0c = *(const short8v*)(PlG + (128 + iP) * 64 + d0P);
  p0d = *(const short8v*)(PlG + (128 + iP) * 64 + d0P + 8);
  __syncthreads();

  f32x4 dacc[8];
#pragma unroll
  for (int mt = 0; mt < 4; ++mt) {  // dd ph0 (proj h1 loads in flight)
    const int mrow = ms * 64 + mt * 16 + llo;
    f32x4 acc = f32x4{0.f, 0.f, 0.f, 0.f};
#pragma unroll
    for (int kb = 0; kb < 2; ++kb) {
      const int c = sw8(mrow, kb * 32 + koff);
      short8v pbh = *(const short8v*)&Ph[mrow][c];
      short8v pbl = *(const short8v*)&Pl[mrow][c];
      acc = MFMA32(pbh, qh[kb], acc);
      acc = MFMA32(pbh, ql[kb], acc);
      acc = MFMA32(pbl, qh[kb], acc);
    }
    dacc[mt] = acc;
  }
  __syncthreads();  // ph0 dd reads done

  // write proj h1; issue ctT h0 loads
  {
    const int c0 = sw8(iP, d0P), c1 = sw8(iP, d0P + 8);
    *(short8v*)&Ph[iP][c0] = p0a;
    *(short8v*)&Ph[iP][c1] = p0b;
    *(short8v*)&Pl[iP][c0] = p0c;
    *(short8v*)&Pl[iP][c1] = p0d;
  }
  {
    const short* gh = ctHG + ((size_t)bh * 64 + eC) * 256 + mgC * 16;
    const short* gl = ctLG + ((size_t)bh * 64 + eC) * 256 + mgC * 16;
    p0a = *(const short8v*)gh;
    p0b = *(const short8v*)(gh + 8);
    p0c = *(const short8v*)gl;
    p0d = *(const short8v*)(gl + 8);
  }
  __syncthreads();

#pragma unroll
  for (int mt = 0; mt < 4; ++mt) {  // dd ph1 (ctT h0 loads in flight)
    const int mrow = ms * 64 + mt * 16 + llo;
    f32x4 acc = f32x4{0.f, 0.f, 0.f, 0.f};
#pragma unroll
    for (int kb = 0; kb < 2; ++kb) {
      const int c = sw8(mrow, kb * 32 + koff);
      short8v pbh = *(const short8v*)&Ph[mrow][c];
      short8v pbl = *(const short8v*)&Pl[mrow][c];
      acc = MFMA32(pbh, qh[kb], acc);
      acc = MFMA32(pbh, ql[kb], acc);
      acc = MFMA32(pbl, qh[kb], acc);
    }
    dacc[4 + mt] = acc;  // dd[m = 128+ms*64+mt*16+lhi*4+jj][r]
  }

  // rowmax over this wave's 128 m's, merged across ms pair via LDS
  {
    float mx = dacc[0][0];
#pragma unroll
    for (int i = 0; i < 8; ++i)
#pragma unroll
      for (int jj = 0; jj < 4; ++jj) mx = fmaxf(mx, dacc[i][jj]);
    mx = fmaxf(mx, __shfl_xor(mx, 16));
    mx = fmaxf(mx, __shfl_xor(mx, 32));
    if (l < 16) atomicMax(&rmaxKey[rt * 16 + l], floatKey(mx));
  }
  __syncthreads();

  // exp -> q' (bf16 hi), den from the SAME rounded weights
  {
    const float shift = dgq + keyToFloat(rmaxKey[r]);
    float den = 0.f;
#pragma unroll
    for (int i = 0; i < 8; ++i) {
      const int m0 = (i >> 2) * 128 + ms * 64 + (i & 3) * 16 + lhi * 4;
      const f32x4 ksv = *(const f32x4*)&kshatL[m0];
      short4v h4;
#pragma unroll
      for (int jj = 0; jj < 4; ++jj) {
        float qv = __expf(dacc[i][jj] - shift) + kEps;
        short hh = f2bf(qv);
        h4[jj] = hh;
        den = fmaf(bf2f(hh), ksv[jj], den);  // consistent with numerator
      }
      const int c = m0 ^ ((r & 31) << 3);
      *(short4v*)&qph[r][c] = h4;
    }
    den += __shfl_xor(den, 16);
    den += __shfl_xor(den, 32);
    if (l < 16) atomicAdd(&denL[rt * 16 + l], den);
  }
  __syncthreads();  // qph/den visible; Ph/Pl dd reads done

  short(*ctTh)[128] = (short(*)[128])Ph;
  short(*ctTl)[128] = (short(*)[128])Pl;
  f32x4 oacc[2] = {f32x4{0.f, 0.f, 0.f, 0.f}, f32x4{0.f, 0.f, 0.f, 0.f}};

  // write ctT h0; issue ctT h1 loads
  {
    *(short8v*)&ctTh[eC][sw16(eC, mgC * 16)] = p0a;
    *(short8v*)&ctTh[eC][sw16(eC, mgC * 16 + 8)] = p0b;
    *(short8v*)&ctTl[eC][sw16(eC, mgC * 16)] = p0c;
    *(short8v*)&ctTl[eC][sw16(eC, mgC * 16 + 8)] = p0d;
  }
  {
    const short* gh = ctHG + ((size_t)bh * 64 + eC) * 256 + 128 + mgC * 16;
    const short* gl = ctLG + ((size_t)bh * 64 + eC) * 256 + 128 + mgC * 16;
    p0a = *(const short8v*)gh;
    p0b = *(const short8v*)(gh + 8);
    p0c = *(const short8v*)gl;
    p0d = *(const short8v*)(gl + 8);
  }
  __syncthreads();

#pragma unroll
  for (int mh2 = 0; mh2 < 2; ++mh2) {
    if (mh2 == 1) {
      __syncthreads();  // out GEMM h0 reads done
      *(short8v*)&ctTh[eC][sw16(eC, mgC * 16)] = p0a;
      *(short8v*)&ctTh[eC][sw16(eC, mgC * 16 + 8)] = p0b;
      *(short8v*)&ctTl[eC][sw16(eC, mgC * 16)] = p0c;
      *(short8v*)&ctTl[eC][sw16(eC, mgC * 16 + 8)] = p0d;
      __syncthreads();
    }
#pragma unroll
    for (int kc = 0; kc < 4; ++kc) {
      const int mb = mh2 * 128 + kc * 32 + koff;
      const int ca = mb ^ ((r & 31) << 3);
      short8v qh8 = *(const short8v*)&qph[r][ca];
#pragma unroll
      for (int et = 0; et < 2; ++et) {
        const int erow = (ms * 2 + et) * 16 + llo;
        const int cb = sw16(erow, kc * 32 + koff);
        short8v th = *(const short8v*)&ctTh[erow][cb];
        short8v tl = *(const short8v*)&ctTl[erow][cb];
        oacc[et] = MFMA32(qh8, th, oacc[et]);
        oacc[et] = MFMA32(qh8, tl, oacc[et]);
      }
    }
  }

  // epilogue
  float inv[4];
#pragma unroll
  for (int jj = 0; jj < 4; ++jj) inv[jj] = 1.0f / denL[rt * 16 + lhi * 4 + jj];
#pragma unroll
  for (int et = 0; et < 2; ++et)
#pragma unroll
    for (int jj = 0; jj < 4; ++jj) {
      const int ro = rt * 16 + lhi * 4 + jj;
      const int e2 = (ms * 2 + et) * 16 + llo;
      out[((size_t)bh * Nn + rb * 64 + ro) * 64 + e2] = oacc[et][jj] * inv[jj];
    }
}

extern "C" void kernel_launch(void* const* d_in, const int* in_sizes, int n_in,
                              void* d_out, int out_size, void* d_ws, size_t ws_size,
                              hipStream_t stream) {
  const float* q = (const float*)d_in[0];
  const float* k = (const float*)d_in[1];
  const float* v = (const float*)d_in[2];
  const float* proj = (const float*)d_in[3];
  float* outp = (float*)d_out;

  char* ws = (char*)d_ws;
  unsigned* stabKey = (unsigned*)(ws + oStab);
  float* EsumG = (float*)(ws + oEsum);
  float* VsumG = (float*)(ws + oVsum);
  float* kshatG = (float*)(ws + oKshat);
  float* ctxEG = (float*)(ws + oCtxE);
  short* ctHG = (short*)(ws + oCtH);
  short* ctLG = (short*)(ws + oCtL);
  short* PhG = (short*)(ws + oPh);
  short* PlG = (short*)(ws + oPl);

  hipMemsetAsync(d_ws, 0, kZeroBytes, stream);
  perf_prep<<<16, 256, 0, stream>>>(proj, PhG, PlG);
  perf_kside<<<dim3(BHn, 16), 512, 0, stream>>>(k, v, PhG, PlG, stabKey, EsumG, VsumG, ctxEG);
  perf_combine<<<BHn, 256, 0, stream>>>(stabKey, EsumG, VsumG, ctxEG, kshatG, ctHG, ctLG);
  perf_qside<<<dim3(BHn, 64), 512, 0, stream>>>(q, PhG, PlG, kshatG, ctHG, ctLG, outp);
}

// Round 13
// 240.289 us; speedup vs baseline: 1.6065x; 1.1218x over previous
//
#include <hip/hip_runtime.h>
#include <hip/hip_bf16.h>
#include <float.h>

// Performer FastAttention (FAVOR+), MFMA bf16-split v8.
// Round 13 (kside only): grid (96,8) 512-row blocks (halves prologue/atomic
// overhead); explicit K-fragment prefetch ping-pong to hide LDS latency in
// the dd->exp->ctx dependent chain; s_setprio(1) around MFMA cluster.
// qside unchanged from r11/r12.

typedef __attribute__((ext_vector_type(8))) short short8v;
typedef __attribute__((ext_vector_type(4))) short short4v;
typedef __attribute__((ext_vector_type(4))) float f32x4;

#define MFMA32(a, b, c) __builtin_amdgcn_mfma_f32_16x16x32_bf16(a, b, c, 0, 0, 0)

#if defined(__has_builtin)
#if __has_builtin(__builtin_amdgcn_mfma_f32_16x16x16bf16_1k)
#define HAVE_MFMA16_1K 1
#endif
#endif
#ifdef HAVE_MFMA16_1K
#define MFMA16K(a, b, c) __builtin_amdgcn_mfma_f32_16x16x16bf16_1k(a, b, c, 0, 0, 0)
#else
static __device__ __forceinline__ f32x4 mfma16k_asm(short4v a, short4v b, f32x4 c) {
  asm("s_nop 1\n\tv_mfma_f32_16x16x16_bf16 %0, %1, %2, %0" : "+v"(c) : "v"(a), "v"(b));
  return c;
}
#define MFMA16K(a, b, c) mfma16k_asm(a, b, c)
#endif

namespace {
constexpr int Nn = 4096, Dd = 64, BHn = 96;
constexpr float kNorm = 0.35355339059327379f;  // 64^-0.25
constexpr float kDiagCoef = 0.0625f;           // 0.5 * 64^-0.5
constexpr float kEps = 1e-4f;

constexpr size_t oStab  = 0;                                   // 96 u32
constexpr size_t oEsum  = 512;                                 // 96*256 f32
constexpr size_t oVsum  = oEsum + (size_t)BHn * 256 * 4;       // 96*64 f32
constexpr size_t oKshat = oVsum + (size_t)BHn * 64 * 4;        // 96*256 f32
constexpr size_t oCtxE  = oKshat + (size_t)BHn * 256 * 4;      // 96*256*64 f32
constexpr size_t oCtH   = oCtxE + (size_t)BHn * 256 * 64 * 4;  // 96*64*256 bf16
constexpr size_t oCtL   = oCtH + (size_t)BHn * 64 * 256 * 2;
constexpr size_t oPh    = oCtL + (size_t)BHn * 64 * 256 * 2;   // 256*64 bf16
constexpr size_t oPl    = oPh + (size_t)256 * 64 * 2;
constexpr size_t kZeroBytes = oCtH;  // zero stab..ctxE accumulators
}

static __device__ __forceinline__ unsigned floatKey(float f) {
  unsigned b = __float_as_uint(f);
  return (b & 0x80000000u) ? ~b : (b | 0x80000000u);
}
static __device__ __forceinline__ float keyToFloat(unsigned k) {
  unsigned b = (k & 0x80000000u) ? (k & 0x7fffffffu) : ~k;
  return __uint_as_float(b);
}
static __device__ __forceinline__ short f2bf(float x) {
  union { __hip_bfloat16 h; short s; } u;
  u.h = __float2bfloat16(x);
  return u.s;
}
static __device__ __forceinline__ float bf2f(short s) {
  return __uint_as_float(((unsigned)(unsigned short)s) << 16);
}
static __device__ __forceinline__ void splitbf(float x, short& h, short& l) {
  h = f2bf(x);
  l = f2bf(x - bf2f(h));
}
static __device__ __forceinline__ int sw8(int row, int col)  { return col ^ ((row & 7) << 3); }
static __device__ __forceinline__ int sw16(int row, int col) { return col ^ ((row & 15) << 3); }

// ---------------------------------------------------------------------------
// prep: split proj into bf16 hi/lo, linear [m][d] layout in ws.
// ---------------------------------------------------------------------------
__global__ void perf_prep(const float* __restrict__ proj, short* __restrict__ Ph,
                          short* __restrict__ Pl) {
  const int i = (blockIdx.x * 256 + threadIdx.x) * 4;  // 16384 elems
  float4 v = *(const float4*)(proj + i);
  float xs[4] = {v.x, v.y, v.z, v.w};
  short4v h, l;
#pragma unroll
  for (int j = 0; j < 4; ++j) {
    short hh, ll;
    splitbf(xs[j], hh, ll);
    h[j] = hh;
    l[j] = ll;
  }
  *(short4v*)(Ph + i) = h;
  *(short4v*)(Pl + i) = l;
}

// ---------------------------------------------------------------------------
// kside: grid (96, 8), block 512 (8 waves). 512 k-rows/block, 8 subs of 64.
// Wave w owns m-strip w*32..+32 (proj frags in regs). dd via 16x16x32 MFMA;
// exp'd accumulator feeds ctx 16x16x16 MFMAs (2-term) directly from regs.
// Double-buffered K/V tiles, 1 barrier/sub, T14 reg prefetch of tile s+2,
// K-fragment ping-pong prefetch, setprio around MFMA cluster.
// ---------------------------------------------------------------------------
__global__ __launch_bounds__(512, 2) void perf_kside(
    const float* __restrict__ K, const float* __restrict__ V,
    const short* __restrict__ PhG, const short* __restrict__ PlG,
    unsigned* __restrict__ stabKey, float* __restrict__ EsumG,
    float* __restrict__ VsumG, float* __restrict__ ctxEG) {
  const int t = threadIdx.x, bh = blockIdx.x, chunk = blockIdx.y;
  const int w = t >> 6, l = t & 63;
  const int lhi = l >> 4, llo = l & 15;
  const int koff = lhi * 8;

  __shared__ short Kh[2][64][64], Kl[2][64][64];
  __shared__ short Vh[2][64][64], Vl[2][64][64];   // V^T: [e][n]
  __shared__ float diag[2][64];
  __shared__ float rpartV[8][64];
  __shared__ float wpmax[8];

  // proj fragments in registers (wave's 32-m strip, both kb slices, hi+lo)
  short8v prh[2][2], prl[2][2];
#pragma unroll
  for (int mt = 0; mt < 2; ++mt)
#pragma unroll
    for (int kb = 0; kb < 2; ++kb) {
      const int m = w * 32 + mt * 16 + llo;
      prh[mt][kb] = *(const short8v*)(PhG + m * 64 + kb * 32 + koff);
      prl[mt][kb] = *(const short8v*)(PlG + m * 64 + kb * 32 + koff);
    }

  float mx = -FLT_MAX, vsum_r = 0.f;
  f32x4 cacc[2][4];
  float es[2] = {0.f, 0.f};
#pragma unroll
  for (int a = 0; a < 2; ++a)
#pragma unroll
    for (int b = 0; b < 4; ++b) cacc[a][b] = f32x4{0.f, 0.f, 0.f, 0.f};

  const size_t base = ((size_t)bh * Nn + chunk * 512) * Dd;
  const int nK = t >> 3, d0K = (t & 7) * 8;
  const int eV = l, n0V = w * 8;
  const float* Kp = K + base + (size_t)nK * 64 + d0K;
  const float* Vp = V + base + (size_t)n0V * 64 + eV;

  float4 ka, kb4;
  float vv[8];

  auto LOADR = [&](int s) {
    const float* kn = Kp + (size_t)s * 64 * 64;
    const float* vn = Vp + (size_t)s * 64 * 64;
    ka = *(const float4*)kn;
    kb4 = *(const float4*)(kn + 4);
#pragma unroll
    for (int i = 0; i < 8; ++i) vv[i] = vn[i * 64];
  };
  auto WRITE = [&](int bi) {
    {  // K split + diag partial
      float xs[8] = {ka.x, ka.y, ka.z, ka.w, kb4.x, kb4.y, kb4.z, kb4.w};
      float s = 0.f;
#pragma unroll
      for (int i = 0; i < 8; ++i) s = fmaf(xs[i], xs[i], s);
      s += __shfl_xor(s, 1); s += __shfl_xor(s, 2); s += __shfl_xor(s, 4);
      if ((t & 7) == 0) diag[bi][nK] = s * kDiagCoef;
      short8v h8, l8;
#pragma unroll
      for (int i = 0; i < 8; ++i) {
        short hh, ll;
        splitbf(kNorm * xs[i], hh, ll);
        h8[i] = hh; l8[i] = ll;
      }
      const int c = sw8(nK, d0K);
      *(short8v*)&Kh[bi][nK][c] = h8;
      *(short8v*)&Kl[bi][nK][c] = l8;
    }
    {  // V^T split (+vsum)
      short8v h8, l8;
#pragma unroll
      for (int i = 0; i < 8; ++i) {
        vsum_r += vv[i];
        short hh, ll;
        splitbf(vv[i], hh, ll);
        h8[i] = hh; l8[i] = ll;
      }
      const int c = sw8(eV, n0V);
      *(short8v*)&Vh[bi][eV][c] = h8;
      *(short8v*)&Vl[bi][eV][c] = l8;
    }
  };

  // prologue: tile0 -> buf0; tile1 loads in flight
  LOADR(0);
  WRITE(0);
  LOADR(1);
  __syncthreads();

  for (int s = 0; s < 8; ++s) {
    const int cur = s & 1;
    if (s < 7) {
      WRITE(cur ^ 1);          // tile s+1 -> other buffer (overlaps compute)
      if (s < 6) LOADR(s + 2); // tile s+2 global loads in flight
    }
    // compute on buf cur — K-frag ping-pong prefetch across b-tiles
    __builtin_amdgcn_s_setprio(1);
    short8v kh2[2][2], kl2[2][2];
    {
      const int arow = llo;
#pragma unroll
      for (int kb = 0; kb < 2; ++kb) {
        const int c = sw8(arow, kb * 32 + koff);
        kh2[0][kb] = *(const short8v*)&Kh[cur][arow][c];
        kl2[0][kb] = *(const short8v*)&Kl[cur][arow][c];
      }
    }
#pragma unroll
    for (int b = 0; b < 4; ++b) {
      const int pb = b & 1, nb = pb ^ 1;
      if (b < 3) {  // prefetch next b-tile's K frags (hides LDS latency)
        const int arow = (b + 1) * 16 + llo;
#pragma unroll
        for (int kb = 0; kb < 2; ++kb) {
          const int c = sw8(arow, kb * 32 + koff);
          kh2[nb][kb] = *(const short8v*)&Kh[cur][arow][c];
          kl2[nb][kb] = *(const short8v*)&Kl[cur][arow][c];
        }
      }
      short4v vh[4], vl[4];
#pragma unroll
      for (int et = 0; et < 4; ++et) {
        const int ecol = et * 16 + llo;
        const int cc = sw8(ecol, b * 16 + lhi * 4);
        vh[et] = *(const short4v*)&Vh[cur][ecol][cc];
        vl[et] = *(const short4v*)&Vl[cur][ecol][cc];
      }
      const f32x4 dg = *(const f32x4*)&diag[cur][b * 16 + lhi * 4];

#pragma unroll
      for (int mt = 0; mt < 2; ++mt) {
        f32x4 acc = f32x4{0.f, 0.f, 0.f, 0.f};
#pragma unroll
        for (int kb = 0; kb < 2; ++kb) {
          acc = MFMA32(kh2[pb][kb], prh[mt][kb], acc);
          acc = MFMA32(kh2[pb][kb], prl[mt][kb], acc);
          acc = MFMA32(kl2[pb][kb], prh[mt][kb], acc);
        }
        short4v h4;
        float esa = 0.f;
#pragma unroll
        for (int jj = 0; jj < 4; ++jj) {
          float dd = acc[jj];
          mx = fmaxf(mx, dd);
          float E = __expf(dd - dg[jj]);
          short hh = f2bf(E);
          h4[jj] = hh;
          esa += bf2f(hh);  // Esum from the SAME rounded E (num/den cancel)
        }
        es[mt] += esa;
        // ctx GEMM 2-term: E_h·V_h + E_h·V_l
#pragma unroll
        for (int et = 0; et < 4; ++et) {
          f32x4 a2 = cacc[mt][et];
          a2 = MFMA16K(h4, vh[et], a2);
          a2 = MFMA16K(h4, vl[et], a2);
          cacc[mt][et] = a2;
        }
      }
    }
    __builtin_amdgcn_s_setprio(0);
    __syncthreads();
  }

  // reductions
#pragma unroll
  for (int off = 32; off; off >>= 1) mx = fmaxf(mx, __shfl_xor(mx, off));
  if (l == 0) wpmax[w] = mx;
#pragma unroll
  for (int mt = 0; mt < 2; ++mt) {
    float v2 = es[mt];
    v2 += __shfl_xor(v2, 16);
    v2 += __shfl_xor(v2, 32);
    if (l < 16) atomicAdd(&EsumG[bh * 256 + w * 32 + mt * 16 + l], v2);
  }
  rpartV[w][l] = vsum_r;
  __syncthreads();
  if (t < 64) {
    float s2 = 0.f;
#pragma unroll
    for (int w2 = 0; w2 < 8; ++w2) s2 += rpartV[w2][t];
    atomicAdd(&VsumG[bh * 64 + t], s2);
  }
  if (t == 0) {
    float b = wpmax[0];
#pragma unroll
    for (int w2 = 1; w2 < 8; ++w2) b = fmaxf(b, wpmax[w2]);
    atomicMax(stabKey + bh, floatKey(b));
  }
#pragma unroll
  for (int mt = 0; mt < 2; ++mt)
#pragma unroll
    for (int et = 0; et < 4; ++et)
#pragma unroll
      for (int jj = 0; jj < 4; ++jj) {
        const int m2 = w * 32 + mt * 16 + lhi * 4 + jj;
        const int e2 = et * 16 + llo;
        atomicAdd(&ctxEG[((size_t)bh * 256 + m2) * 64 + e2], cacc[mt][et][jj]);
      }
}

// ---------------------------------------------------------------------------
// combine: kshat[m] = e^{-stab}*Esum + eps*N; ctxhat -> transposed bf16 pair.
// ---------------------------------------------------------------------------
__global__ __launch_bounds__(256) void perf_combine(
    const unsigned* __restrict__ stabKey, const float* __restrict__ EsumG,
    const float* __restrict__ VsumG, const float* __restrict__ ctxEG,
    float* __restrict__ kshatG, short* __restrict__ ctHG, short* __restrict__ ctLG) {
  const int bh = blockIdx.x, t = threadIdx.x;
  const float esc = __expf(-keyToFloat(stabKey[bh]));
  kshatG[bh * 256 + t] = esc * EsumG[bh * 256 + t] + kEps * 4096.0f;
  for (int e = 0; e < 64; ++e) {
    const float v2 = esc * ctxEG[((size_t)bh * 256 + t) * 64 + e] + kEps * VsumG[bh * 64 + e];
    short hh, ll;
    splitbf(v2, hh, ll);
    ctHG[((size_t)bh * 64 + e) * 256 + t] = hh;
    ctLG[((size_t)bh * 64 + e) * 256 + t] = ll;
  }
}

// ---------------------------------------------------------------------------
// qside: grid (96, 64), block 512. 64 q-rows/block. LDS 65.5K. (unchanged r12)
// ---------------------------------------------------------------------------
__global__ __launch_bounds__(512, 2) void perf_qside(
    const float* __restrict__ Q, const short* __restrict__ PhG,
    const short* __restrict__ PlG, const float* __restrict__ kshatG,
    const short* __restrict__ ctHG, const short* __restrict__ ctLG,
    float* __restrict__ out) {
  const int t = threadIdx.x, bh = blockIdx.x, rb = blockIdx.y;
  const int w = t >> 6, l = t & 63;
  const int rt = w & 3, ms = w >> 2;
  const int lhi = l >> 4, llo = l & 15;
  const int koff = lhi * 8;

  __shared__ short Ph[128][64], Pl[128][64];  // per-phase proj; reused as ctT[64][128]
  __shared__ short qph[64][256];              // q' bf16 (hi only)
  __shared__ float kshatL[256];
  __shared__ unsigned rmaxKey[64];
  __shared__ float denL[64];

  // staging coords
  const int iP = t >> 2, d0P = (t & 3) * 16;          // proj staging
  const int eC = t >> 3, mgC = t & 7;                 // ctT staging

  // issue proj h0 loads immediately
  short8v p0a = *(const short8v*)(PhG + iP * 64 + d0P);
  short8v p0b = *(const short8v*)(PhG + iP * 64 + d0P + 8);
  short8v p0c = *(const short8v*)(PlG + iP * 64 + d0P);
  short8v p0d = *(const short8v*)(PlG + iP * 64 + d0P + 8);

  if (t < 64) { rmaxKey[t] = 0u; denL[t] = 0.f; }
  if (t < 256) kshatL[t] = kshatG[bh * 256 + t];

  const int r = rt * 16 + llo;  // this lane's q-row

  // Q fragments + diag (global direct; folded norm) — overlaps proj loads
  short8v qh[2], ql[2];
  float dgq;
  {
    const float* qs = Q + ((size_t)bh * Nn + rb * 64 + r) * 64 + koff;
    float4 a0 = *(const float4*)qs;
    float4 a1 = *(const float4*)(qs + 4);
    float4 b0 = *(const float4*)(qs + 32);
    float4 b1 = *(const float4*)(qs + 36);
    float xs[16] = {a0.x, a0.y, a0.z, a0.w, a1.x, a1.y, a1.z, a1.w,
                    b0.x, b0.y, b0.z, b0.w, b1.x, b1.y, b1.z, b1.w};
    float s = 0.f;
#pragma unroll
    for (int i = 0; i < 16; ++i) s = fmaf(xs[i], xs[i], s);
    s += __shfl_xor(s, 16);
    s += __shfl_xor(s, 32);
    dgq = s * kDiagCoef;
#pragma unroll
    for (int kb = 0; kb < 2; ++kb) {
      short8v h8, l8;
#pragma unroll
      for (int i = 0; i < 8; ++i) {
        short hh, ll;
        splitbf(kNorm * xs[kb * 8 + i], hh, ll);
        h8[i] = hh; l8[i] = ll;
      }
      qh[kb] = h8; ql[kb] = l8;
    }
  }
  __syncthreads();  // init visible

  // write proj h0; issue proj h1 loads
  {
    const int c0 = sw8(iP, d0P), c1 = sw8(iP, d0P + 8);
    *(short8v*)&Ph[iP][c0] = p0a;
    *(short8v*)&Ph[iP][c1] = p0b;
    *(short8v*)&Pl[iP][c0] = p0c;
    *(short8v*)&Pl[iP][c1] = p0d;
  }
  p0a = *(const short8v*)(PhG + (128 + iP) * 64 + d0P);
  p0b = *(const short8v*)(PhG + (128 + iP) * 64 + d0P + 8);
  p0c = *(const short8v*)(PlG + (128 + iP) * 64 + d0P);
  p0d = *(const short8v*)(PlG + (128 + iP) * 64 + d0P + 8);
  __syncthreads();

  f32x4 dacc[8];
#pragma unroll
  for (int mt = 0; mt < 4; ++mt) {  // dd ph0 (proj h1 loads in flight)
    const int mrow = ms * 64 + mt * 16 + llo;
    f32x4 acc = f32x4{0.f, 0.f, 0.f, 0.f};
#pragma unroll
    for (int kb = 0; kb < 2; ++kb) {
      const int c = sw8(mrow, kb * 32 + koff);
      short8v pbh = *(const short8v*)&Ph[mrow][c];
      short8v pbl = *(const short8v*)&Pl[mrow][c];
      acc = MFMA32(pbh, qh[kb], acc);
      acc = MFMA32(pbh, ql[kb], acc);
      acc = MFMA32(pbl, qh[kb], acc);
    }
    dacc[mt] = acc;
  }
  __syncthreads();  // ph0 dd reads done

  // write proj h1; issue ctT h0 loads
  {
    const int c0 = sw8(iP, d0P), c1 = sw8(iP, d0P + 8);
    *(short8v*)&Ph[iP][c0] = p0a;
    *(short8v*)&Ph[iP][c1] = p0b;
    *(short8v*)&Pl[iP][c0] = p0c;
    *(short8v*)&Pl[iP][c1] = p0d;
  }
  {
    const short* gh = ctHG + ((size_t)bh * 64 + eC) * 256 + mgC * 16;
    const short* gl = ctLG + ((size_t)bh * 64 + eC) * 256 + mgC * 16;
    p0a = *(const short8v*)gh;
    p0b = *(const short8v*)(gh + 8);
    p0c = *(const short8v*)gl;
    p0d = *(const short8v*)(gl + 8);
  }
  __syncthreads();

#pragma unroll
  for (int mt = 0; mt < 4; ++mt) {  // dd ph1 (ctT h0 loads in flight)
    const int mrow = ms * 64 + mt * 16 + llo;
    f32x4 acc = f32x4{0.f, 0.f, 0.f, 0.f};
#pragma unroll
    for (int kb = 0; kb < 2; ++kb) {
      const int c = sw8(mrow, kb * 32 + koff);
      short8v pbh = *(const short8v*)&Ph[mrow][c];
      short8v pbl = *(const short8v*)&Pl[mrow][c];
      acc = MFMA32(pbh, qh[kb], acc);
      acc = MFMA32(pbh, ql[kb], acc);
      acc = MFMA32(pbl, qh[kb], acc);
    }
    dacc[4 + mt] = acc;  // dd[m = 128+ms*64+mt*16+lhi*4+jj][r]
  }

  // rowmax over this wave's 128 m's, merged across ms pair via LDS
  {
    float mx = dacc[0][0];
#pragma unroll
    for (int i = 0; i < 8; ++i)
#pragma unroll
      for (int jj = 0; jj < 4; ++jj) mx = fmaxf(mx, dacc[i][jj]);
    mx = fmaxf(mx, __shfl_xor(mx, 16));
    mx = fmaxf(mx, __shfl_xor(mx, 32));
    if (l < 16) atomicMax(&rmaxKey[rt * 16 + l], floatKey(mx));
  }
  __syncthreads();

  // exp -> q' (bf16 hi), den from the SAME rounded weights
  {
    const float shift = dgq + keyToFloat(rmaxKey[r]);
    float den = 0.f;
#pragma unroll
    for (int i = 0; i < 8; ++i) {
      const int m0 = (i >> 2) * 128 + ms * 64 + (i & 3) * 16 + lhi * 4;
      const f32x4 ksv = *(const f32x4*)&kshatL[m0];
      short4v h4;
#pragma unroll
      for (int jj = 0; jj < 4; ++jj) {
        float qv = __expf(dacc[i][jj] - shift) + kEps;
        short hh = f2bf(qv);
        h4[jj] = hh;
        den = fmaf(bf2f(hh), ksv[jj], den);  // consistent with numerator
      }
      const int c = m0 ^ ((r & 31) << 3);
      *(short4v*)&qph[r][c] = h4;
    }
    den += __shfl_xor(den, 16);
    den += __shfl_xor(den, 32);
    if (l < 16) atomicAdd(&denL[rt * 16 + l], den);
  }
  __syncthreads();  // qph/den visible; Ph/Pl dd reads done

  short(*ctTh)[128] = (short(*)[128])Ph;
  short(*ctTl)[128] = (short(*)[128])Pl;
  f32x4 oacc[2] = {f32x4{0.f, 0.f, 0.f, 0.f}, f32x4{0.f, 0.f, 0.f, 0.f}};

  // write ctT h0; issue ctT h1 loads
  {
    *(short8v*)&ctTh[eC][sw16(eC, mgC * 16)] = p0a;
    *(short8v*)&ctTh[eC][sw16(eC, mgC * 16 + 8)] = p0b;
    *(short8v*)&ctTl[eC][sw16(eC, mgC * 16)] = p0c;
    *(short8v*)&ctTl[eC][sw16(eC, mgC * 16 + 8)] = p0d;
  }
  {
    const short* gh = ctHG + ((size_t)bh * 64 + eC) * 256 + 128 + mgC * 16;
    const short* gl = ctLG + ((size_t)bh * 64 + eC) * 256 + 128 + mgC * 16;
    p0a = *(const short8v*)gh;
    p0b = *(const short8v*)(gh + 8);
    p0c = *(const short8v*)gl;
    p0d = *(const short8v*)(gl + 8);
  }
  __syncthreads();

#pragma unroll
  for (int mh2 = 0; mh2 < 2; ++mh2) {
    if (mh2 == 1) {
      __syncthreads();  // out GEMM h0 reads done
      *(short8v*)&ctTh[eC][sw16(eC, mgC * 16)] = p0a;
      *(short8v*)&ctTh[eC][sw16(eC, mgC * 16 + 8)] = p0b;
      *(short8v*)&ctTl[eC][sw16(eC, mgC * 16)] = p0c;
      *(short8v*)&ctTl[eC][sw16(eC, mgC * 16 + 8)] = p0d;
      __syncthreads();
    }
#pragma unroll
    for (int kc = 0; kc < 4; ++kc) {
      const int mb = mh2 * 128 + kc * 32 + koff;
      const int ca = mb ^ ((r & 31) << 3);
      short8v qh8 = *(const short8v*)&qph[r][ca];
#pragma unroll
      for (int et = 0; et < 2; ++et) {
        const int erow = (ms * 2 + et) * 16 + llo;
        const int cb = sw16(erow, kc * 32 + koff);
        short8v th = *(const short8v*)&ctTh[erow][cb];
        short8v tl = *(const short8v*)&ctTl[erow][cb];
        oacc[et] = MFMA32(qh8, th, oacc[et]);
        oacc[et] = MFMA32(qh8, tl, oacc[et]);
      }
    }
  }

  // epilogue
  float inv[4];
#pragma unroll
  for (int jj = 0; jj < 4; ++jj) inv[jj] = 1.0f / denL[rt * 16 + lhi * 4 + jj];
#pragma unroll
  for (int et = 0; et < 2; ++et)
#pragma unroll
    for (int jj = 0; jj < 4; ++jj) {
      const int ro = rt * 16 + lhi * 4 + jj;
      const int e2 = (ms * 2 + et) * 16 + llo;
      out[((size_t)bh * Nn + rb * 64 + ro) * 64 + e2] = oacc[et][jj] * inv[jj];
    }
}

extern "C" void kernel_launch(void* const* d_in, const int* in_sizes, int n_in,
                              void* d_out, int out_size, void* d_ws, size_t ws_size,
                              hipStream_t stream) {
  const float* q = (const float*)d_in[0];
  const float* k = (const float*)d_in[1];
  const float* v = (const float*)d_in[2];
  const float* proj = (const float*)d_in[3];
  float* outp = (float*)d_out;

  char* ws = (char*)d_ws;
  unsigned* stabKey = (unsigned*)(ws + oStab);
  float* EsumG = (float*)(ws + oEsum);
  float* VsumG = (float*)(ws + oVsum);
  float* kshatG = (float*)(ws + oKshat);
  float* ctxEG = (float*)(ws + oCtxE);
  short* ctHG = (short*)(ws + oCtH);
  short* ctLG = (short*)(ws + oCtL);
  short* PhG = (short*)(ws + oPh);
  short* PlG = (short*)(ws + oPl);

  hipMemsetAsync(d_ws, 0, kZeroBytes, stream);
  perf_prep<<<16, 256, 0, stream>>>(proj, PhG, PlG);
  perf_kside<<<dim3(BHn, 8), 512, 0, stream>>>(k, v, PhG, PlG, stabKey, EsumG, VsumG, ctxEG);
  perf_combine<<<BHn, 256, 0, stream>>>(stabKey, EsumG, VsumG, ctxEG, kshatG, ctHG, ctLG);
  perf_qside<<<dim3(BHn, 64), 512, 0, stream>>>(q, PhG, PlG, kshatG, ctHG, ctLG, outp);
}